// Round 13
// baseline (173.611 us; speedup 1.0000x reference)
//
#include <hip/hip_runtime.h>
#include <math.h>

#define NSEQ 4096
#define EDIM 512
#define NHEAD 8
#define DHEAD 64

// LESSON (R4, R8): direct-from-global MFMA fragment loads regress vs
// LDS-staged ds_read_b128 fragments, even when perfectly coalesced/tiled.
// LESSON (R10): BK=128 in the projection GEMM regresses vs BK=64.
// LESSON (R11): attention occupancy 18->23% changed nothing -- LDS-traffic
// bound; cut bytes (wider per-wave q-tiles, R12: 53->46us), not add waves.
// R13: casts folded into GEMM staging (fp32 loads + cvt) -- one fewer kernel.

typedef unsigned short ushort_t;
typedef __attribute__((ext_vector_type(8))) _Float16 half8;    // 8 f16 (4 VGPRs)
typedef __attribute__((ext_vector_type(2))) __fp16 pkhalf2;    // cvt_pkrtz out
typedef __attribute__((ext_vector_type(4))) float floatx4;     // MFMA C/D
typedef __attribute__((ext_vector_type(8))) ushort_t us8;
typedef __attribute__((ext_vector_type(4))) ushort_t us4;

#define C2SCALE 0.02254211f  // log2(e)/64, folded into Q at projection

__device__ __forceinline__ ushort_t f2h(float x) {  // RNE float->f16
  union { _Float16 h; ushort_t u; } v;
  v.h = (_Float16)x;
  return v.u;
}

__device__ __forceinline__ us4 f4h(float4 t) {
  us4 o;
  o[0] = f2h(t.x); o[1] = f2h(t.y); o[2] = f2h(t.z); o[3] = f2h(t.w);
  return o;
}

#if __has_builtin(__builtin_amdgcn_exp2f)
#define EXP2F(x) __builtin_amdgcn_exp2f(x)
#else
#define EXP2F(x) exp2f(x)
#endif

// ---------------------------------------------------------------------------
// Fused QKV f16 MFMA NT GEMM; W and X read as fp32, converted during LDS
// staging (removes the separate cast kernel). BK=64, 64o x 128n tile.
// z=0: Q -> f16 (E,N) scaled by C2SCALE; z=1: K -> (N,E); z=2: V -> (E,N).
// ---------------------------------------------------------------------------
__global__ __launch_bounds__(256, 3) void gemm_qkv(
    const float* __restrict__ WQw, const float* __restrict__ WQb,
    const float* __restrict__ WKw, const float* __restrict__ WKb,
    const float* __restrict__ WVw, const float* __restrict__ WVb,
    const float* __restrict__ Xw, ushort_t* __restrict__ Qb,
    ushort_t* __restrict__ Kb, ushort_t* __restrict__ Vb) {
  __shared__ __align__(16) char smem[27648];
  ushort_t(*Ws)[72] = (ushort_t(*)[72])smem;           // [64][72]
  ushort_t(*Xs)[72] = (ushort_t(*)[72])(smem + 9216);  // [128][72]

  const int tid = threadIdx.x;
  const int w = tid >> 6, lane = tid & 63, quad = lane >> 4, l16 = lane & 15;
  const int o0 = blockIdx.y * 64, n0 = blockIdx.x * 128, z = blockIdx.z;
  const int wr = tid >> 2, wseg = (tid & 3) * 16;  // W stage: 64 rows x 16 k
  const int xr = tid >> 1, xseg = (tid & 1) * 32;  // X stage: 128 rows x 32 k

  const float* Wf = (z == 0) ? WQw : (z == 1) ? WKw : WVw;
  const float* bias = (z == 0) ? WQb : (z == 1) ? WKb : WVb;

  floatx4 acc[4][2];
#pragma unroll
  for (int ot = 0; ot < 4; ++ot)
#pragma unroll
    for (int nt = 0; nt < 2; ++nt) {
      acc[ot][nt][0] = 0.f; acc[ot][nt][1] = 0.f;
      acc[ot][nt][2] = 0.f; acc[ot][nt][3] = 0.f;
    }

  for (int k0 = 0; k0 < EDIM; k0 += 64) {
    us4 wv[4], xv[8];
#pragma unroll
    for (int j = 0; j < 4; ++j)
      wv[j] = f4h(*(const float4*)(Wf + (o0 + wr) * 512 + k0 + wseg + j * 4));
#pragma unroll
    for (int j = 0; j < 8; ++j)
      xv[j] = f4h(*(const float4*)(Xw + (n0 + xr) * 512 + k0 + xseg + j * 4));
    __syncthreads();  // previous iteration's LDS reads complete
#pragma unroll
    for (int j = 0; j < 4; ++j) *(us4*)&Ws[wr][wseg + j * 4] = wv[j];
#pragma unroll
    for (int j = 0; j < 8; ++j) *(us4*)&Xs[xr][xseg + j * 4] = xv[j];
    __syncthreads();

    half8 a[2][4], b[2][2];
#pragma unroll
    for (int kh = 0; kh < 2; ++kh) {
#pragma unroll
      for (int ot = 0; ot < 4; ++ot)
        a[kh][ot] = *(const half8*)&Ws[ot * 16 + l16][kh * 32 + quad * 8];
#pragma unroll
      for (int nt = 0; nt < 2; ++nt)
        b[kh][nt] =
            *(const half8*)&Xs[w * 32 + nt * 16 + l16][kh * 32 + quad * 8];
    }
#pragma unroll
    for (int kh = 0; kh < 2; ++kh)
#pragma unroll
      for (int ot = 0; ot < 4; ++ot)
#pragma unroll
        for (int nt = 0; nt < 2; ++nt)
          acc[ot][nt] = __builtin_amdgcn_mfma_f32_16x16x32_f16(
              a[kh][ot], b[kh][nt], acc[ot][nt], 0, 0, 0);
  }

  __syncthreads();  // staging reads done; smem reused for epilogue
  float bo[4][4];
#pragma unroll
  for (int ot = 0; ot < 4; ++ot)
#pragma unroll
    for (int r = 0; r < 4; ++r)
      bo[ot][r] = bias[o0 + ot * 16 + quad * 4 + r];

  if (z != 1) {  // f16 (E,N): Q (scaled) or V
    ushort_t(*Cs)[136] = (ushort_t(*)[136])smem;
    const float scale = (z == 0) ? C2SCALE : 1.0f;
#pragma unroll
    for (int ot = 0; ot < 4; ++ot)
#pragma unroll
      for (int nt = 0; nt < 2; ++nt)
#pragma unroll
        for (int r = 0; r < 4; ++r)
          Cs[ot * 16 + quad * 4 + r][w * 32 + nt * 16 + l16] =
              f2h((acc[ot][nt][r] + bo[ot][r]) * scale);
    __syncthreads();
    ushort_t* C = (z == 0) ? Qb : Vb;
    const int row = tid >> 2, seg = (tid & 3) * 32;
#pragma unroll
    for (int j = 0; j < 4; ++j)
      *(us8*)(C + (o0 + row) * 4096 + n0 + seg + j * 8) =
          *(const us8*)&Cs[row][seg + j * 8];
  } else {  // f16 (N,E): K
    ushort_t(*Cs)[72] = (ushort_t(*)[72])smem;
#pragma unroll
    for (int ot = 0; ot < 4; ++ot)
#pragma unroll
      for (int nt = 0; nt < 2; ++nt)
#pragma unroll
        for (int r = 0; r < 4; ++r)
          Cs[w * 32 + nt * 16 + l16][ot * 16 + quad * 4 + r] =
              f2h(acc[ot][nt][r] + bo[ot][r]);
    __syncthreads();
    const int row = tid >> 1, seg = (tid & 1) * 32;
#pragma unroll
    for (int j = 0; j < 4; ++j)
      *(us8*)(Kb + (n0 + row) * 512 + o0 + seg + j * 8) =
          *(const us8*)&Cs[row][seg + j * 8];
  }
}

// ---------------------------------------------------------------------------
// Output projection with FUSED combine over 4 split-K partials; W read fp32
// and converted during staging. Z[n][e] = (sum_z Zp[z][n][e]) / (sum_z
// Lp[z][h][n]), h = e>>6. fp32 (N,E) out. 64o x 64n tile, 512 blocks.
// ---------------------------------------------------------------------------
__global__ __launch_bounds__(256, 2) void gemm_out(
    const float* __restrict__ Wf, const ushort_t* __restrict__ Zp,
    const float* __restrict__ Lp, const float* __restrict__ bias,
    float* __restrict__ C) {
  __shared__ __align__(16) char smem[18432];
  ushort_t(*Ws)[72] = (ushort_t(*)[72])smem;           // [64][72]
  ushort_t(*Xs)[72] = (ushort_t(*)[72])(smem + 9216);  // [64][72]

  const int tid = threadIdx.x;
  const int w = tid >> 6, lane = tid & 63, quad = lane >> 4, l16 = lane & 15;
  const int o0 = blockIdx.y * 64, n0 = blockIdx.x * 64;
  const int lr = tid >> 2, lseg = (tid & 3) * 16;

  floatx4 acc[4];
#pragma unroll
  for (int ot = 0; ot < 4; ++ot) {
    acc[ot][0] = 0.f; acc[ot][1] = 0.f; acc[ot][2] = 0.f; acc[ot][3] = 0.f;
  }

  for (int k0 = 0; k0 < EDIM; k0 += 64) {
    const int hh = k0 >> 6;
    us4 wv[4];
#pragma unroll
    for (int j = 0; j < 4; ++j)
      wv[j] = f4h(*(const float4*)(Wf + (o0 + lr) * 512 + k0 + lseg + j * 4));
    float za[8], zb[8];
#pragma unroll
    for (int j = 0; j < 8; ++j) { za[j] = 0.f; zb[j] = 0.f; }
    float lsum = 0.f;
#pragma unroll
    for (int zz = 0; zz < 4; ++zz) {
      const half8 zv0 =
          *(const half8*)(Zp + zz * 2097152 + (n0 + lr) * 512 + k0 + lseg);
      const half8 zv1 =
          *(const half8*)(Zp + zz * 2097152 + (n0 + lr) * 512 + k0 + lseg + 8);
#pragma unroll
      for (int j = 0; j < 8; ++j) {
        za[j] += (float)zv0[j];
        zb[j] += (float)zv1[j];
      }
      lsum += Lp[zz * 32768 + hh * 4096 + n0 + lr];
    }
    const float inv = 1.0f / lsum;
    us8 x0, x1;
#pragma unroll
    for (int j = 0; j < 8; ++j) {
      x0[j] = f2h(za[j] * inv);
      x1[j] = f2h(zb[j] * inv);
    }
    __syncthreads();
#pragma unroll
    for (int j = 0; j < 4; ++j) *(us4*)&Ws[lr][lseg + j * 4] = wv[j];
    *(us8*)&Xs[lr][lseg] = x0;
    *(us8*)&Xs[lr][lseg + 8] = x1;
    __syncthreads();

    half8 a[2][4], b[2];
#pragma unroll
    for (int kh = 0; kh < 2; ++kh) {
#pragma unroll
      for (int ot = 0; ot < 4; ++ot)
        a[kh][ot] = *(const half8*)&Ws[ot * 16 + l16][kh * 32 + quad * 8];
      b[kh] = *(const half8*)&Xs[w * 16 + l16][kh * 32 + quad * 8];
    }
#pragma unroll
    for (int kh = 0; kh < 2; ++kh)
#pragma unroll
      for (int ot = 0; ot < 4; ++ot)
        acc[ot] = __builtin_amdgcn_mfma_f32_16x16x32_f16(a[kh][ot], b[kh],
                                                         acc[ot], 0, 0, 0);
  }

  __syncthreads();
  float(*Cs)[68] = (float(*)[68])smem;
#pragma unroll
  for (int ot = 0; ot < 4; ++ot) {
    floatx4 v = acc[ot];
#pragma unroll
    for (int r = 0; r < 4; ++r) v[r] += bias[o0 + ot * 16 + quad * 4 + r];
    *(floatx4*)&Cs[w * 16 + l16][ot * 16 + quad * 4] = v;
  }
  __syncthreads();
  const int row = tid >> 2, seg = (tid & 3) * 16;
#pragma unroll
  for (int j = 0; j < 4; ++j)
    *(float4*)(C + (n0 + row) * 512 + o0 + seg + j * 4) =
        *(const float4*)&Cs[row][seg + j * 4];
}

// ---------------------------------------------------------------------------
// V (f16, scrambled (E,N)) -> Vt[h][d][m]
// ---------------------------------------------------------------------------
__global__ __launch_bounds__(256) void transpose_v(
    const ushort_t* __restrict__ Vb, ushort_t* __restrict__ Vt) {
  __shared__ ushort_t Ts[64][72];
  const int tid = threadIdx.x;
  const int h = blockIdx.y;
  const int m0 = blockIdx.x * 64;
  const ushort_t* src = Vb + h * 262144 + m0 * 64;
  {
    const int r = tid >> 2, c = (tid & 3) << 4;
    const us8 a = *(const us8*)(src + r * 64 + c);
    const us8 b = *(const us8*)(src + r * 64 + c + 8);
    *(us8*)&Ts[r][c] = a;
    *(us8*)&Ts[r][c + 8] = b;
  }
  __syncthreads();
  const int d = tid >> 2, r0 = (tid & 3) << 4;
  us8 o0, o1;
#pragma unroll
  for (int j = 0; j < 8; ++j) {
    o0[j] = Ts[r0 + j][d];
    o1[j] = Ts[r0 + 8 + j][d];
  }
  ushort_t* dst = Vt + h * 262144 + d * 4096 + m0 + r0;
  *(us8*)(dst) = o0;
  *(us8*)(dst + 8) = o1;
}

// ---------------------------------------------------------------------------
// Flash attention (R12 known-good): f16 MFMA, transposed-score, LDS-staged
// K/V, max-free softmax, rowsum via ones-MFMA, f16 Z^T partials, split-K 4.
// WIDE WAVES: each wave owns 64 q-rows (4 q-tiles), block = 256 q-rows;
// K/V fragments read once per m-pair, reused across all 4 q-tiles.
// ---------------------------------------------------------------------------
__global__ __launch_bounds__(256, 2) void attn_mfma(
    const ushort_t* __restrict__ Qb, const ushort_t* __restrict__ Kb,
    const ushort_t* __restrict__ Vt, ushort_t* __restrict__ Zp,
    float* __restrict__ Lp) {
  __shared__ __align__(16) ushort_t Ks[128][72];    // K chunk [m][d]
  __shared__ __align__(16) ushort_t Vts[64][136];   // V^T chunk [d][m]
  __shared__ __align__(16) ushort_t Ps[8][16][40];  // per (w, qt&1): P [n][32m]

  const int tid = threadIdx.x;
  const int w = tid >> 6;
  const int lane = tid & 63;
  const int quad = lane >> 4;
  const int l16 = lane & 15;
  const int h = blockIdx.y;
  const int n0 = blockIdx.x * 256;
  const int z = blockIdx.z;
  const int mbase = z * (NSEQ / 4);

  half8 qf[4][2];
#pragma unroll
  for (int qt = 0; qt < 4; ++qt) {
    const ushort_t* qsrc = Qb + h * 262144 + (n0 + w * 64 + qt * 16 + l16) * 64;
    qf[qt][0] = *(const half8*)(qsrc + quad * 8);
    qf[qt][1] = *(const half8*)(qsrc + 32 + quad * 8);
  }

  half8 ones;
#pragma unroll
  for (int j = 0; j < 8; ++j) ones[j] = (_Float16)1.0f;

  floatx4 zacc[4][4];
  floatx4 sumacc[4];
#pragma unroll
  for (int qt = 0; qt < 4; ++qt) {
    sumacc[qt][0] = 0.f; sumacc[qt][1] = 0.f;
    sumacc[qt][2] = 0.f; sumacc[qt][3] = 0.f;
#pragma unroll
    for (int dt = 0; dt < 4; ++dt) {
      zacc[qt][dt][0] = 0.f; zacc[qt][dt][1] = 0.f;
      zacc[qt][dt][2] = 0.f; zacc[qt][dt][3] = 0.f;
    }
  }

  const int kr = tid >> 2;
  const int kc = (tid & 3) << 4;
  const int vd = tid >> 2;
  const int vm = (tid & 3) << 5;

  for (int m0 = 0; m0 < NSEQ / 4; m0 += 128) {
    const ushort_t* ksrc = Kb + h * 262144 + (mbase + m0) * 64;
    const ushort_t* vsrc = Vt + h * 262144 + vd * 4096 + mbase + m0 + vm;
    us8 kst[4], vst[4];
    kst[0] = *(const us8*)(ksrc + kr * 64 + kc);
    kst[1] = *(const us8*)(ksrc + kr * 64 + kc + 8);
    kst[2] = *(const us8*)(ksrc + (64 + kr) * 64 + kc);
    kst[3] = *(const us8*)(ksrc + (64 + kr) * 64 + kc + 8);
#pragma unroll
    for (int j = 0; j < 4; ++j) vst[j] = *(const us8*)(vsrc + j * 8);

    __syncthreads();  // previous chunk's LDS reads complete
    *(us8*)&Ks[kr][kc] = kst[0];
    *(us8*)&Ks[kr][kc + 8] = kst[1];
    *(us8*)&Ks[64 + kr][kc] = kst[2];
    *(us8*)&Ks[64 + kr][kc + 8] = kst[3];
#pragma unroll
    for (int j = 0; j < 4; ++j) *(us8*)&Vts[vd][vm + j * 8] = vst[j];
    __syncthreads();

#pragma unroll
    for (int t = 0; t < 4; ++t) {
      // ---- K fragments for m-pair (mt = 2t, 2t+1); reused by all 4 qt ----
      const half8 kfA0 = *(const half8*)&Ks[(2 * t) * 16 + l16][quad * 8];
      const half8 kfA1 = *(const half8*)&Ks[(2 * t) * 16 + l16][32 + quad * 8];
      const half8 kfB0 = *(const half8*)&Ks[(2 * t + 1) * 16 + l16][quad * 8];
      const half8 kfB1 =
          *(const half8*)&Ks[(2 * t + 1) * 16 + l16][32 + quad * 8];
      // ---- V^T fragments for this m-pair; reused by all 4 qt ----
      half8 vf[4];
#pragma unroll
      for (int dt = 0; dt < 4; ++dt)
        vf[dt] = *(const half8*)&Vts[dt * 16 + l16][t * 32 + quad * 8];

#pragma unroll
      for (int qt = 0; qt < 4; ++qt) {
        floatx4 sA = {0.f, 0.f, 0.f, 0.f};
        sA = __builtin_amdgcn_mfma_f32_16x16x32_f16(kfA0, qf[qt][0], sA, 0, 0, 0);
        sA = __builtin_amdgcn_mfma_f32_16x16x32_f16(kfA1, qf[qt][1], sA, 0, 0, 0);
        floatx4 sB = {0.f, 0.f, 0.f, 0.f};
        sB = __builtin_amdgcn_mfma_f32_16x16x32_f16(kfB0, qf[qt][0], sB, 0, 0, 0);
        sB = __builtin_amdgcn_mfma_f32_16x16x32_f16(kfB1, qf[qt][1], sB, 0, 0, 0);
        union { pkhalf2 h; unsigned u; } a01, a23, b01, b23;
        a01.h = __builtin_amdgcn_cvt_pkrtz(EXP2F(sA[0]), EXP2F(sA[1]));
        a23.h = __builtin_amdgcn_cvt_pkrtz(EXP2F(sA[2]), EXP2F(sA[3]));
        b01.h = __builtin_amdgcn_cvt_pkrtz(EXP2F(sB[0]), EXP2F(sB[1]));
        b23.h = __builtin_amdgcn_cvt_pkrtz(EXP2F(sB[2]), EXP2F(sB[3]));
        ushort_t* slot = &Ps[w * 2 + (qt & 1)][l16][0];
        *(unsigned*)(slot + quad * 4) = a01.u;
        *(unsigned*)(slot + quad * 4 + 2) = a23.u;
        *(unsigned*)(slot + 16 + quad * 4) = b01.u;
        *(unsigned*)(slot + 16 + quad * 4 + 2) = b23.u;
        // same-wave LDS RAW: write->read ordered via lgkmcnt (no barrier)
        const half8 pf = *(const half8*)(slot + quad * 8);
        sumacc[qt] =
            __builtin_amdgcn_mfma_f32_16x16x32_f16(ones, pf, sumacc[qt], 0, 0, 0);
#pragma unroll
        for (int dt = 0; dt < 4; ++dt)
          zacc[qt][dt] = __builtin_amdgcn_mfma_f32_16x16x32_f16(
              vf[dt], pf, zacc[qt][dt], 0, 0, 0);
      }
    }
  }

  // ---- partial epilogue: Z^T partials as f16, row-sums fp32 ----
#pragma unroll
  for (int qt = 0; qt < 4; ++qt) {
    const int n = n0 + w * 64 + qt * 16 + l16;
    ushort_t* dst = Zp + z * 2097152 + n * EDIM + h * 64;
#pragma unroll
    for (int dt = 0; dt < 4; ++dt) {
      us4 o;
#pragma unroll
      for (int r = 0; r < 4; ++r) o[r] = f2h(zacc[qt][dt][r]);
      *(us4*)(dst + dt * 16 + quad * 4) = o;
    }
    if (quad == 0) Lp[z * 32768 + h * 4096 + n] = sumacc[qt][0];
  }
}

extern "C" void kernel_launch(void* const* d_in, const int* in_sizes, int n_in,
                              void* d_out, int out_size, void* d_ws,
                              size_t ws_size, hipStream_t stream) {
  const float* inp = (const float*)d_in[0];
  const float* WKw = (const float*)d_in[1];
  const float* WKb = (const float*)d_in[2];
  const float* WQw = (const float*)d_in[3];
  const float* WQb = (const float*)d_in[4];
  const float* WVw = (const float*)d_in[5];
  const float* WVb = (const float*)d_in[6];
  const float* WZw = (const float*)d_in[7];
  const float* WZb = (const float*)d_in[8];

  char* ws = (char*)d_ws;
  const size_t MB = 1 << 20;
  ushort_t* Qb = (ushort_t*)(ws);             // 4MB f16 (E,N) scrambled, *C2
  ushort_t* Kb = (ushort_t*)(ws + 4 * MB);    // 4MB f16 (N,E)
  ushort_t* Vb = (ushort_t*)(ws + 8 * MB);    // 4MB f16 (E,N)
  ushort_t* Vtb = (ushort_t*)(ws + 12 * MB);  // 4MB f16 [h][d][m]
  ushort_t* Zp = (ushort_t*)(ws + 16 * MB);   // 16MB: [4][4096][512] f16
  float* Lp = (float*)(ws + 32 * MB);         // 512KB: [4][8][4096]

  gemm_qkv<<<dim3(NSEQ / 128, EDIM / 64, 3), 256, 0, stream>>>(
      WQw, WQb, WKw, WKb, WVw, WVb, inp, Qb, Kb, Vb);

  transpose_v<<<dim3(NSEQ / 64, NHEAD), 256, 0, stream>>>(Vb, Vtb);

  attn_mfma<<<dim3(NSEQ / 256, NHEAD, 4), 256, 0, stream>>>(Qb, Kb, Vtb, Zp,
                                                            Lp);

  gemm_out<<<dim3(NSEQ / 64, EDIM / 64), 256, 0, stream>>>(WZw, Zp, Lp, WZb,
                                                           (float*)d_out);
}

// Round 14
// 155.911 us; speedup vs baseline: 1.1135x; 1.1135x over previous
//
#include <hip/hip_runtime.h>
#include <math.h>

#define NSEQ 4096
#define EDIM 512
#define NHEAD 8
#define DHEAD 64

// LESSON (R4, R8): direct-from-global MFMA fragment loads regress vs
// LDS-staged ds_read_b128 fragments, even when perfectly coalesced/tiled.
// LESSON (R10): BK=128 in the projection GEMM regresses vs BK=64.
// LESSON (R11/R12): attention is LDS-traffic bound; wider per-wave q-tiles
// (64 q/wave) cut fragment re-reads 2x (53->46us). Occupancy adds nothing.
// LESSON (R13): folding fp32 casts into GEMM staging regresses ~18us --
// keep the cast kernel; prep work belongs off the staging critical path.

typedef unsigned short ushort_t;
typedef __attribute__((ext_vector_type(8))) _Float16 half8;    // 8 f16 (4 VGPRs)
typedef __attribute__((ext_vector_type(2))) __fp16 pkhalf2;    // cvt_pkrtz out
typedef __attribute__((ext_vector_type(4))) float floatx4;     // MFMA C/D
typedef __attribute__((ext_vector_type(8))) ushort_t us8;
typedef __attribute__((ext_vector_type(4))) ushort_t us4;

#define C2SCALE 0.02254211f  // log2(e)/64, folded into Q at projection

__device__ __forceinline__ ushort_t f2h(float x) {  // RNE float->f16
  union { _Float16 h; ushort_t u; } v;
  v.h = (_Float16)x;
  return v.u;
}

#if __has_builtin(__builtin_amdgcn_exp2f)
#define EXP2F(x) __builtin_amdgcn_exp2f(x)
#else
#define EXP2F(x) exp2f(x)
#endif

// ---------------------------------------------------------------------------
// fused fp32 -> f16 cast for inp (2048 blocks) + 4 weight mats (1024 blocks)
// ---------------------------------------------------------------------------
__global__ __launch_bounds__(256) void cast_all(
    const float* __restrict__ inp, ushort_t* __restrict__ Xf,
    const float* __restrict__ w0, const float* __restrict__ w1,
    const float* __restrict__ w2, const float* __restrict__ w3,
    ushort_t* __restrict__ d0, ushort_t* __restrict__ d1,
    ushort_t* __restrict__ d2, ushort_t* __restrict__ d3) {
  const int bid = blockIdx.x;
  const float* s;
  ushort_t* d;
  int blk;
  if (bid < 2048) {
    s = inp; d = Xf; blk = bid;
  } else {
    const int seg = (bid - 2048) >> 8;
    blk = (bid - 2048) & 255;
    switch (seg) {
      case 0: s = w0; d = d0; break;
      case 1: s = w1; d = d1; break;
      case 2: s = w2; d = d2; break;
      default: s = w3; d = d3; break;
    }
  }
  const int i = (blk * 256 + threadIdx.x) * 4;
  const float4 v = *(const float4*)(s + i);
  us4 o;
  o[0] = f2h(v.x); o[1] = f2h(v.y); o[2] = f2h(v.z); o[3] = f2h(v.w);
  *(us4*)(d + i) = o;
}

// ---------------------------------------------------------------------------
// Fused QKV single-plane f16 MFMA NT GEMM, LDS-staged, BK=64, 3 blocks/CU.
// 64o x 128n tile. z=0: Q -> f16 (E,N) scaled by C2SCALE; z=1: K -> (N,E);
// z=2: V -> (E,N).
// ---------------------------------------------------------------------------
__global__ __launch_bounds__(256, 3) void gemm_qkv(
    const ushort_t* __restrict__ WQf, const float* __restrict__ WQb,
    const ushort_t* __restrict__ WKf, const float* __restrict__ WKb,
    const ushort_t* __restrict__ WVf, const float* __restrict__ WVb,
    const ushort_t* __restrict__ Xf, ushort_t* __restrict__ Qb,
    ushort_t* __restrict__ Kb, ushort_t* __restrict__ Vb) {
  __shared__ __align__(16) char smem[27648];
  ushort_t(*Ws)[72] = (ushort_t(*)[72])smem;           // [64][72]
  ushort_t(*Xs)[72] = (ushort_t(*)[72])(smem + 9216);  // [128][72]

  const int tid = threadIdx.x;
  const int w = tid >> 6, lane = tid & 63, quad = lane >> 4, l16 = lane & 15;
  const int o0 = blockIdx.y * 64, n0 = blockIdx.x * 128, z = blockIdx.z;
  const int wr = tid >> 2, wseg = (tid & 3) * 16;  // W stage: 64 rows x 16 k
  const int xr = tid >> 1, xseg = (tid & 1) * 32;  // X stage: 128 rows x 32 k

  const ushort_t* Wf = (z == 0) ? WQf : (z == 1) ? WKf : WVf;
  const float* bias = (z == 0) ? WQb : (z == 1) ? WKb : WVb;

  floatx4 acc[4][2];
#pragma unroll
  for (int ot = 0; ot < 4; ++ot)
#pragma unroll
    for (int nt = 0; nt < 2; ++nt) {
      acc[ot][nt][0] = 0.f; acc[ot][nt][1] = 0.f;
      acc[ot][nt][2] = 0.f; acc[ot][nt][3] = 0.f;
    }

  for (int k0 = 0; k0 < EDIM; k0 += 64) {
    const us8 w0 = *(const us8*)(Wf + (o0 + wr) * 512 + k0 + wseg);
    const us8 w1 = *(const us8*)(Wf + (o0 + wr) * 512 + k0 + wseg + 8);
    us8 xv[4];
#pragma unroll
    for (int j = 0; j < 4; ++j)
      xv[j] = *(const us8*)(Xf + (n0 + xr) * 512 + k0 + xseg + j * 8);
    __syncthreads();  // previous iteration's LDS reads complete
    *(us8*)&Ws[wr][wseg] = w0;
    *(us8*)&Ws[wr][wseg + 8] = w1;
#pragma unroll
    for (int j = 0; j < 4; ++j) *(us8*)&Xs[xr][xseg + j * 8] = xv[j];
    __syncthreads();

    half8 a[2][4], b[2][2];
#pragma unroll
    for (int kh = 0; kh < 2; ++kh) {
#pragma unroll
      for (int ot = 0; ot < 4; ++ot)
        a[kh][ot] = *(const half8*)&Ws[ot * 16 + l16][kh * 32 + quad * 8];
#pragma unroll
      for (int nt = 0; nt < 2; ++nt)
        b[kh][nt] =
            *(const half8*)&Xs[w * 32 + nt * 16 + l16][kh * 32 + quad * 8];
    }
#pragma unroll
    for (int kh = 0; kh < 2; ++kh)
#pragma unroll
      for (int ot = 0; ot < 4; ++ot)
#pragma unroll
        for (int nt = 0; nt < 2; ++nt)
          acc[ot][nt] = __builtin_amdgcn_mfma_f32_16x16x32_f16(
              a[kh][ot], b[kh][nt], acc[ot][nt], 0, 0, 0);
  }

  __syncthreads();  // staging reads done; smem reused for epilogue
  float bo[4][4];
#pragma unroll
  for (int ot = 0; ot < 4; ++ot)
#pragma unroll
    for (int r = 0; r < 4; ++r)
      bo[ot][r] = bias[o0 + ot * 16 + quad * 4 + r];

  if (z != 1) {  // f16 (E,N): Q (scaled) or V
    ushort_t(*Cs)[136] = (ushort_t(*)[136])smem;
    const float scale = (z == 0) ? C2SCALE : 1.0f;
#pragma unroll
    for (int ot = 0; ot < 4; ++ot)
#pragma unroll
      for (int nt = 0; nt < 2; ++nt)
#pragma unroll
        for (int r = 0; r < 4; ++r)
          Cs[ot * 16 + quad * 4 + r][w * 32 + nt * 16 + l16] =
              f2h((acc[ot][nt][r] + bo[ot][r]) * scale);
    __syncthreads();
    ushort_t* C = (z == 0) ? Qb : Vb;
    const int row = tid >> 2, seg = (tid & 3) * 32;
#pragma unroll
    for (int j = 0; j < 4; ++j)
      *(us8*)(C + (o0 + row) * 4096 + n0 + seg + j * 8) =
          *(const us8*)&Cs[row][seg + j * 8];
  } else {  // f16 (N,E): K
    ushort_t(*Cs)[72] = (ushort_t(*)[72])smem;
#pragma unroll
    for (int ot = 0; ot < 4; ++ot)
#pragma unroll
      for (int nt = 0; nt < 2; ++nt)
#pragma unroll
        for (int r = 0; r < 4; ++r)
          Cs[w * 32 + nt * 16 + l16][ot * 16 + quad * 4 + r] =
              f2h(acc[ot][nt][r] + bo[ot][r]);
    __syncthreads();
    const int row = tid >> 1, seg = (tid & 1) * 32;
#pragma unroll
    for (int j = 0; j < 4; ++j)
      *(us8*)(Kb + (n0 + row) * 512 + o0 + seg + j * 8) =
          *(const us8*)&Cs[row][seg + j * 8];
  }
}

// ---------------------------------------------------------------------------
// Output projection with FUSED combine over 4 split-K partials:
// Z[n][e] = (sum_z Zp[z][n][e]) / (sum_z Lp[z][h][n]), h = e>>6.
// fp32 (N,E) out. 64o x 64n tile, 512 blocks.
// ---------------------------------------------------------------------------
__global__ __launch_bounds__(256, 2) void gemm_out(
    const ushort_t* __restrict__ Wf, const ushort_t* __restrict__ Zp,
    const float* __restrict__ Lp, const float* __restrict__ bias,
    float* __restrict__ C) {
  __shared__ __align__(16) char smem[18432];
  ushort_t(*Ws)[72] = (ushort_t(*)[72])smem;           // [64][72]
  ushort_t(*Xs)[72] = (ushort_t(*)[72])(smem + 9216);  // [64][72]

  const int tid = threadIdx.x;
  const int w = tid >> 6, lane = tid & 63, quad = lane >> 4, l16 = lane & 15;
  const int o0 = blockIdx.y * 64, n0 = blockIdx.x * 64;
  const int lr = tid >> 2, lseg = (tid & 3) * 16;

  floatx4 acc[4];
#pragma unroll
  for (int ot = 0; ot < 4; ++ot) {
    acc[ot][0] = 0.f; acc[ot][1] = 0.f; acc[ot][2] = 0.f; acc[ot][3] = 0.f;
  }

  for (int k0 = 0; k0 < EDIM; k0 += 64) {
    const int hh = k0 >> 6;
    const us8 w0 = *(const us8*)(Wf + (o0 + lr) * 512 + k0 + lseg);
    const us8 w1 = *(const us8*)(Wf + (o0 + lr) * 512 + k0 + lseg + 8);
    float za[8], zb[8];
#pragma unroll
    for (int j = 0; j < 8; ++j) { za[j] = 0.f; zb[j] = 0.f; }
    float lsum = 0.f;
#pragma unroll
    for (int zz = 0; zz < 4; ++zz) {
      const half8 zv0 =
          *(const half8*)(Zp + zz * 2097152 + (n0 + lr) * 512 + k0 + lseg);
      const half8 zv1 =
          *(const half8*)(Zp + zz * 2097152 + (n0 + lr) * 512 + k0 + lseg + 8);
#pragma unroll
      for (int j = 0; j < 8; ++j) {
        za[j] += (float)zv0[j];
        zb[j] += (float)zv1[j];
      }
      lsum += Lp[zz * 32768 + hh * 4096 + n0 + lr];
    }
    const float inv = 1.0f / lsum;
    us8 x0, x1;
#pragma unroll
    for (int j = 0; j < 8; ++j) {
      x0[j] = f2h(za[j] * inv);
      x1[j] = f2h(zb[j] * inv);
    }
    __syncthreads();
    *(us8*)&Ws[lr][lseg] = w0;
    *(us8*)&Ws[lr][lseg + 8] = w1;
    *(us8*)&Xs[lr][lseg] = x0;
    *(us8*)&Xs[lr][lseg + 8] = x1;
    __syncthreads();

    half8 a[2][4], b[2];
#pragma unroll
    for (int kh = 0; kh < 2; ++kh) {
#pragma unroll
      for (int ot = 0; ot < 4; ++ot)
        a[kh][ot] = *(const half8*)&Ws[ot * 16 + l16][kh * 32 + quad * 8];
      b[kh] = *(const half8*)&Xs[w * 16 + l16][kh * 32 + quad * 8];
    }
#pragma unroll
    for (int kh = 0; kh < 2; ++kh)
#pragma unroll
      for (int ot = 0; ot < 4; ++ot)
        acc[ot] = __builtin_amdgcn_mfma_f32_16x16x32_f16(a[kh][ot], b[kh],
                                                         acc[ot], 0, 0, 0);
  }

  __syncthreads();
  float(*Cs)[68] = (float(*)[68])smem;
#pragma unroll
  for (int ot = 0; ot < 4; ++ot) {
    floatx4 v = acc[ot];
#pragma unroll
    for (int r = 0; r < 4; ++r) v[r] += bias[o0 + ot * 16 + quad * 4 + r];
    *(floatx4*)&Cs[w * 16 + l16][ot * 16 + quad * 4] = v;
  }
  __syncthreads();
  const int row = tid >> 2, seg = (tid & 3) * 16;
#pragma unroll
  for (int j = 0; j < 4; ++j)
    *(float4*)(C + (n0 + row) * 512 + o0 + seg + j * 4) =
        *(const float4*)&Cs[row][seg + j * 4];
}

// ---------------------------------------------------------------------------
// V (f16, scrambled (E,N)) -> Vt[h][d][m]
// ---------------------------------------------------------------------------
__global__ __launch_bounds__(256) void transpose_v(
    const ushort_t* __restrict__ Vb, ushort_t* __restrict__ Vt) {
  __shared__ ushort_t Ts[64][72];
  const int tid = threadIdx.x;
  const int h = blockIdx.y;
  const int m0 = blockIdx.x * 64;
  const ushort_t* src = Vb + h * 262144 + m0 * 64;
  {
    const int r = tid >> 2, c = (tid & 3) << 4;
    const us8 a = *(const us8*)(src + r * 64 + c);
    const us8 b = *(const us8*)(src + r * 64 + c + 8);
    *(us8*)&Ts[r][c] = a;
    *(us8*)&Ts[r][c + 8] = b;
  }
  __syncthreads();
  const int d = tid >> 2, r0 = (tid & 3) << 4;
  us8 o0, o1;
#pragma unroll
  for (int j = 0; j < 8; ++j) {
    o0[j] = Ts[r0 + j][d];
    o1[j] = Ts[r0 + 8 + j][d];
  }
  ushort_t* dst = Vt + h * 262144 + d * 4096 + m0 + r0;
  *(us8*)(dst) = o0;
  *(us8*)(dst + 8) = o1;
}

// ---------------------------------------------------------------------------
// Flash attention: f16 MFMA, transposed-score, LDS-staged K/V, max-free
// softmax, rowsum via ones-MFMA, f16 Z^T partials, split-K 4.
// WIDE WAVES (R12): each wave owns 64 q-rows (4 q-tiles), block = 256 q-rows;
// K/V fragments read once per m-pair, reused across all 4 q-tiles.
// R14: 256-KEY CHUNKS -- 4 staging iterations instead of 8, halving the
// barrier-drain count. LDS 76 KB -> 2 blocks/CU (grid is 2/CU anyway).
// ---------------------------------------------------------------------------
__global__ __launch_bounds__(256, 2) void attn_mfma(
    const ushort_t* __restrict__ Qb, const ushort_t* __restrict__ Kb,
    const ushort_t* __restrict__ Vt, ushort_t* __restrict__ Zp,
    float* __restrict__ Lp) {
  __shared__ __align__(16) ushort_t Ks[256][72];    // K chunk [m][d]
  __shared__ __align__(16) ushort_t Vts[64][264];   // V^T chunk [d][m]
  __shared__ __align__(16) ushort_t Ps[8][16][40];  // per (w, qt&1): P [n][32m]

  const int tid = threadIdx.x;
  const int w = tid >> 6;
  const int lane = tid & 63;
  const int quad = lane >> 4;
  const int l16 = lane & 15;
  const int h = blockIdx.y;
  const int n0 = blockIdx.x * 256;
  const int z = blockIdx.z;
  const int mbase = z * (NSEQ / 4);

  half8 qf[4][2];
#pragma unroll
  for (int qt = 0; qt < 4; ++qt) {
    const ushort_t* qsrc = Qb + h * 262144 + (n0 + w * 64 + qt * 16 + l16) * 64;
    qf[qt][0] = *(const half8*)(qsrc + quad * 8);
    qf[qt][1] = *(const half8*)(qsrc + 32 + quad * 8);
  }

  half8 ones;
#pragma unroll
  for (int j = 0; j < 8; ++j) ones[j] = (_Float16)1.0f;

  floatx4 zacc[4][4];
  floatx4 sumacc[4];
#pragma unroll
  for (int qt = 0; qt < 4; ++qt) {
    sumacc[qt][0] = 0.f; sumacc[qt][1] = 0.f;
    sumacc[qt][2] = 0.f; sumacc[qt][3] = 0.f;
#pragma unroll
    for (int dt = 0; dt < 4; ++dt) {
      zacc[qt][dt][0] = 0.f; zacc[qt][dt][1] = 0.f;
      zacc[qt][dt][2] = 0.f; zacc[qt][dt][3] = 0.f;
    }
  }

  const int kr = tid >> 2;         // K stage row base (0..63; +64/128/192)
  const int kc = (tid & 3) << 4;   // K stage d base
  const int vd = tid >> 2;         // Vt stage row d
  const int vm = (tid & 3) << 6;   // Vt stage m base (64 m per lane)

  for (int m0 = 0; m0 < NSEQ / 4; m0 += 256) {
    const ushort_t* ksrc = Kb + h * 262144 + (mbase + m0) * 64;
    const ushort_t* vsrc = Vt + h * 262144 + vd * 4096 + mbase + m0 + vm;
    us8 kst[8], vst[8];
#pragma unroll
    for (int g = 0; g < 4; ++g) {
      kst[2 * g] = *(const us8*)(ksrc + (g * 64 + kr) * 64 + kc);
      kst[2 * g + 1] = *(const us8*)(ksrc + (g * 64 + kr) * 64 + kc + 8);
    }
#pragma unroll
    for (int j = 0; j < 8; ++j) vst[j] = *(const us8*)(vsrc + j * 8);

    __syncthreads();  // previous chunk's LDS reads complete
#pragma unroll
    for (int g = 0; g < 4; ++g) {
      *(us8*)&Ks[g * 64 + kr][kc] = kst[2 * g];
      *(us8*)&Ks[g * 64 + kr][kc + 8] = kst[2 * g + 1];
    }
#pragma unroll
    for (int j = 0; j < 8; ++j) *(us8*)&Vts[vd][vm + j * 8] = vst[j];
    __syncthreads();

#pragma unroll
    for (int t = 0; t < 8; ++t) {
      // ---- K fragments for m-pair (mt = 2t, 2t+1); reused by all 4 qt ----
      const half8 kfA0 = *(const half8*)&Ks[(2 * t) * 16 + l16][quad * 8];
      const half8 kfA1 = *(const half8*)&Ks[(2 * t) * 16 + l16][32 + quad * 8];
      const half8 kfB0 = *(const half8*)&Ks[(2 * t + 1) * 16 + l16][quad * 8];
      const half8 kfB1 =
          *(const half8*)&Ks[(2 * t + 1) * 16 + l16][32 + quad * 8];
      // ---- V^T fragments for this m-pair; reused by all 4 qt ----
      half8 vf[4];
#pragma unroll
      for (int dt = 0; dt < 4; ++dt)
        vf[dt] = *(const half8*)&Vts[dt * 16 + l16][t * 32 + quad * 8];

#pragma unroll
      for (int qt = 0; qt < 4; ++qt) {
        floatx4 sA = {0.f, 0.f, 0.f, 0.f};
        sA = __builtin_amdgcn_mfma_f32_16x16x32_f16(kfA0, qf[qt][0], sA, 0, 0, 0);
        sA = __builtin_amdgcn_mfma_f32_16x16x32_f16(kfA1, qf[qt][1], sA, 0, 0, 0);
        floatx4 sB = {0.f, 0.f, 0.f, 0.f};
        sB = __builtin_amdgcn_mfma_f32_16x16x32_f16(kfB0, qf[qt][0], sB, 0, 0, 0);
        sB = __builtin_amdgcn_mfma_f32_16x16x32_f16(kfB1, qf[qt][1], sB, 0, 0, 0);
        union { pkhalf2 h; unsigned u; } a01, a23, b01, b23;
        a01.h = __builtin_amdgcn_cvt_pkrtz(EXP2F(sA[0]), EXP2F(sA[1]));
        a23.h = __builtin_amdgcn_cvt_pkrtz(EXP2F(sA[2]), EXP2F(sA[3]));
        b01.h = __builtin_amdgcn_cvt_pkrtz(EXP2F(sB[0]), EXP2F(sB[1]));
        b23.h = __builtin_amdgcn_cvt_pkrtz(EXP2F(sB[2]), EXP2F(sB[3]));
        ushort_t* slot = &Ps[w * 2 + (qt & 1)][l16][0];
        *(unsigned*)(slot + quad * 4) = a01.u;
        *(unsigned*)(slot + quad * 4 + 2) = a23.u;
        *(unsigned*)(slot + 16 + quad * 4) = b01.u;
        *(unsigned*)(slot + 16 + quad * 4 + 2) = b23.u;
        // same-wave LDS RAW: write->read ordered via lgkmcnt (no barrier)
        const half8 pf = *(const half8*)(slot + quad * 8);
        sumacc[qt] =
            __builtin_amdgcn_mfma_f32_16x16x32_f16(ones, pf, sumacc[qt], 0, 0, 0);
#pragma unroll
        for (int dt = 0; dt < 4; ++dt)
          zacc[qt][dt] = __builtin_amdgcn_mfma_f32_16x16x32_f16(
              vf[dt], pf, zacc[qt][dt], 0, 0, 0);
      }
    }
  }

  // ---- partial epilogue: Z^T partials as f16, row-sums fp32 ----
#pragma unroll
  for (int qt = 0; qt < 4; ++qt) {
    const int n = n0 + w * 64 + qt * 16 + l16;
    ushort_t* dst = Zp + z * 2097152 + n * EDIM + h * 64;
#pragma unroll
    for (int dt = 0; dt < 4; ++dt) {
      us4 o;
#pragma unroll
      for (int r = 0; r < 4; ++r) o[r] = f2h(zacc[qt][dt][r]);
      *(us4*)(dst + dt * 16 + quad * 4) = o;
    }
    if (quad == 0) Lp[z * 32768 + h * 4096 + n] = sumacc[qt][0];
  }
}

extern "C" void kernel_launch(void* const* d_in, const int* in_sizes, int n_in,
                              void* d_out, int out_size, void* d_ws,
                              size_t ws_size, hipStream_t stream) {
  const float* inp = (const float*)d_in[0];
  const float* WKw = (const float*)d_in[1];
  const float* WKb = (const float*)d_in[2];
  const float* WQw = (const float*)d_in[3];
  const float* WQb = (const float*)d_in[4];
  const float* WVw = (const float*)d_in[5];
  const float* WVb = (const float*)d_in[6];
  const float* WZw = (const float*)d_in[7];
  const float* WZb = (const float*)d_in[8];

  char* ws = (char*)d_ws;
  const size_t MB = 1 << 20;
  ushort_t* Xf = (ushort_t*)(ws);                        // 4MB
  ushort_t* WQf = (ushort_t*)(ws + 4 * MB);              // 512KB each
  ushort_t* WKf = (ushort_t*)(ws + 4 * MB + 512 * 1024);
  ushort_t* WVf = (ushort_t*)(ws + 5 * MB);
  ushort_t* WZf = (ushort_t*)(ws + 5 * MB + 512 * 1024);
  ushort_t* Qb = (ushort_t*)(ws + 6 * MB);    // 4MB f16 (E,N) scrambled, *C2
  ushort_t* Kb = (ushort_t*)(ws + 10 * MB);   // 4MB f16 (N,E)
  ushort_t* Vb = (ushort_t*)(ws + 14 * MB);   // 4MB f16 (E,N)
  ushort_t* Vtb = (ushort_t*)(ws + 18 * MB);  // 4MB f16 [h][d][m]
  ushort_t* Zp = (ushort_t*)(ws + 22 * MB);   // 16MB: [4][4096][512] f16
  float* Lp = (float*)(ws + 38 * MB);         // 512KB: [4][8][4096]

  cast_all<<<3072, 256, 0, stream>>>(inp, Xf, WKw, WQw, WVw, WZw, WKf, WQf,
                                     WVf, WZf);

  gemm_qkv<<<dim3(NSEQ / 128, EDIM / 64, 3), 256, 0, stream>>>(
      WQf, WQb, WKf, WKb, WVf, WVb, Xf, Qb, Kb, Vb);

  transpose_v<<<dim3(NSEQ / 64, NHEAD), 256, 0, stream>>>(Vb, Vtb);

  attn_mfma<<<dim3(NSEQ / 256, NHEAD, 4), 256, 0, stream>>>(Qb, Kb, Vtb, Zp,
                                                            Lp);

  gemm_out<<<dim3(NSEQ / 64, EDIM / 64), 256, 0, stream>>>(WZf, Zp, Lp, WZb,
                                                           (float*)d_out);
}

// Round 15
// 151.179 us; speedup vs baseline: 1.1484x; 1.0313x over previous
//
#include <hip/hip_runtime.h>
#include <math.h>

#define NSEQ 4096
#define EDIM 512
#define NHEAD 8
#define DHEAD 64

// LESSON (R4, R8): direct-from-global MFMA fragment loads regress vs
// LDS-staged ds_read_b128 fragments, even when perfectly coalesced/tiled.
// LESSON (R10/R14): bigger K-chunks (BK=128 gemm, 256-key attn) regress --
// LDS size/occupancy and conflicts beat barrier-amortization on this chip.
// LESSON (R11/R12): attention is LDS-traffic bound; wider per-wave q-tiles
// (64 q/wave) cut fragment re-reads 2x (53->46us). Occupancy adds nothing.
// LESSON (R13): folding fp32 casts into GEMM staging regresses ~18us --
// keep the cast kernel; prep work belongs off the staging critical path.
// R15: V-projection emits Vt[h][d][m] directly (strided n-tile) -- the
// transpose_v kernel is gone.

typedef unsigned short ushort_t;
typedef __attribute__((ext_vector_type(8))) _Float16 half8;    // 8 f16 (4 VGPRs)
typedef __attribute__((ext_vector_type(2))) __fp16 pkhalf2;    // cvt_pkrtz out
typedef __attribute__((ext_vector_type(4))) float floatx4;     // MFMA C/D
typedef __attribute__((ext_vector_type(8))) ushort_t us8;
typedef __attribute__((ext_vector_type(4))) ushort_t us4;

#define C2SCALE 0.02254211f  // log2(e)/64, folded into Q at projection

__device__ __forceinline__ ushort_t f2h(float x) {  // RNE float->f16
  union { _Float16 h; ushort_t u; } v;
  v.h = (_Float16)x;
  return v.u;
}

#if __has_builtin(__builtin_amdgcn_exp2f)
#define EXP2F(x) __builtin_amdgcn_exp2f(x)
#else
#define EXP2F(x) exp2f(x)
#endif

// ---------------------------------------------------------------------------
// fused fp32 -> f16 cast for inp (2048 blocks) + 4 weight mats (1024 blocks)
// ---------------------------------------------------------------------------
__global__ __launch_bounds__(256) void cast_all(
    const float* __restrict__ inp, ushort_t* __restrict__ Xf,
    const float* __restrict__ w0, const float* __restrict__ w1,
    const float* __restrict__ w2, const float* __restrict__ w3,
    ushort_t* __restrict__ d0, ushort_t* __restrict__ d1,
    ushort_t* __restrict__ d2, ushort_t* __restrict__ d3) {
  const int bid = blockIdx.x;
  const float* s;
  ushort_t* d;
  int blk;
  if (bid < 2048) {
    s = inp; d = Xf; blk = bid;
  } else {
    const int seg = (bid - 2048) >> 8;
    blk = (bid - 2048) & 255;
    switch (seg) {
      case 0: s = w0; d = d0; break;
      case 1: s = w1; d = d1; break;
      case 2: s = w2; d = d2; break;
      default: s = w3; d = d3; break;
    }
  }
  const int i = (blk * 256 + threadIdx.x) * 4;
  const float4 v = *(const float4*)(s + i);
  us4 o;
  o[0] = f2h(v.x); o[1] = f2h(v.y); o[2] = f2h(v.z); o[3] = f2h(v.w);
  *(us4*)(d + i) = o;
}

// ---------------------------------------------------------------------------
// Fused QKV single-plane f16 MFMA NT GEMM, LDS-staged, BK=64, 3 blocks/CU.
// 64o x 128n tile.
// z=0: Q -> f16 (E,N) scaled by C2SCALE.   z=1: K -> f16 (N,E).
// z=2: V -> f16 Vt[h][d][m] DIRECTLY: n-tile is the strided set
//      {n = nh*64 + bx*2 + dd : nh in [0,64), dd in {0,1}} so each (o-row, d)
//      yields 64 consecutive m (m = (o&63)*64 + nh) -> 128B coalesced runs.
// ---------------------------------------------------------------------------
__global__ __launch_bounds__(256, 3) void gemm_qkv(
    const ushort_t* __restrict__ WQf, const float* __restrict__ WQb,
    const ushort_t* __restrict__ WKf, const float* __restrict__ WKb,
    const ushort_t* __restrict__ WVf, const float* __restrict__ WVb,
    const ushort_t* __restrict__ Xf, ushort_t* __restrict__ Qb,
    ushort_t* __restrict__ Kb, ushort_t* __restrict__ Vt) {
  __shared__ __align__(16) char smem[27648];
  ushort_t(*Ws)[72] = (ushort_t(*)[72])smem;           // [64][72]
  ushort_t(*Xs)[72] = (ushort_t(*)[72])(smem + 9216);  // [128][72]

  const int tid = threadIdx.x;
  const int w = tid >> 6, lane = tid & 63, quad = lane >> 4, l16 = lane & 15;
  const int o0 = blockIdx.y * 64, n0 = blockIdx.x * 128, z = blockIdx.z;
  const int wr = tid >> 2, wseg = (tid & 3) * 16;  // W stage: 64 rows x 16 k
  const int xr = tid >> 1, xseg = (tid & 1) * 32;  // X stage: 128 rows x 32 k
  // z==2: tile-local row r maps to global n = (r>>1)*64 + bx*2 + (r&1)
  const int xrow = (z == 2)
                       ? ((xr >> 1) * 64 + blockIdx.x * 2 + (xr & 1))
                       : (n0 + xr);

  const ushort_t* Wf = (z == 0) ? WQf : (z == 1) ? WKf : WVf;
  const float* bias = (z == 0) ? WQb : (z == 1) ? WKb : WVb;

  floatx4 acc[4][2];
#pragma unroll
  for (int ot = 0; ot < 4; ++ot)
#pragma unroll
    for (int nt = 0; nt < 2; ++nt) {
      acc[ot][nt][0] = 0.f; acc[ot][nt][1] = 0.f;
      acc[ot][nt][2] = 0.f; acc[ot][nt][3] = 0.f;
    }

  for (int k0 = 0; k0 < EDIM; k0 += 64) {
    const us8 w0 = *(const us8*)(Wf + (o0 + wr) * 512 + k0 + wseg);
    const us8 w1 = *(const us8*)(Wf + (o0 + wr) * 512 + k0 + wseg + 8);
    us8 xv[4];
#pragma unroll
    for (int j = 0; j < 4; ++j)
      xv[j] = *(const us8*)(Xf + xrow * 512 + k0 + xseg + j * 8);
    __syncthreads();  // previous iteration's LDS reads complete
    *(us8*)&Ws[wr][wseg] = w0;
    *(us8*)&Ws[wr][wseg + 8] = w1;
#pragma unroll
    for (int j = 0; j < 4; ++j) *(us8*)&Xs[xr][xseg + j * 8] = xv[j];
    __syncthreads();

    half8 a[2][4], b[2][2];
#pragma unroll
    for (int kh = 0; kh < 2; ++kh) {
#pragma unroll
      for (int ot = 0; ot < 4; ++ot)
        a[kh][ot] = *(const half8*)&Ws[ot * 16 + l16][kh * 32 + quad * 8];
#pragma unroll
      for (int nt = 0; nt < 2; ++nt)
        b[kh][nt] =
            *(const half8*)&Xs[w * 32 + nt * 16 + l16][kh * 32 + quad * 8];
    }
#pragma unroll
    for (int kh = 0; kh < 2; ++kh)
#pragma unroll
      for (int ot = 0; ot < 4; ++ot)
#pragma unroll
        for (int nt = 0; nt < 2; ++nt)
          acc[ot][nt] = __builtin_amdgcn_mfma_f32_16x16x32_f16(
              a[kh][ot], b[kh][nt], acc[ot][nt], 0, 0, 0);
  }

  __syncthreads();  // staging reads done; smem reused for epilogue
  float bo[4][4];
#pragma unroll
  for (int ot = 0; ot < 4; ++ot)
#pragma unroll
    for (int r = 0; r < 4; ++r)
      bo[ot][r] = bias[o0 + ot * 16 + quad * 4 + r];

  if (z == 0) {  // Q: f16 (E,N), scaled
    ushort_t(*Cs)[136] = (ushort_t(*)[136])smem;
#pragma unroll
    for (int ot = 0; ot < 4; ++ot)
#pragma unroll
      for (int nt = 0; nt < 2; ++nt)
#pragma unroll
        for (int r = 0; r < 4; ++r)
          Cs[ot * 16 + quad * 4 + r][w * 32 + nt * 16 + l16] =
              f2h((acc[ot][nt][r] + bo[ot][r]) * C2SCALE);
    __syncthreads();
    const int row = tid >> 2, seg = (tid & 3) * 32;
#pragma unroll
    for (int j = 0; j < 4; ++j)
      *(us8*)(Qb + (o0 + row) * 4096 + n0 + seg + j * 8) =
          *(const us8*)&Cs[row][seg + j * 8];
  } else if (z == 1) {  // K: f16 (N,E)
    ushort_t(*Cs)[72] = (ushort_t(*)[72])smem;
#pragma unroll
    for (int ot = 0; ot < 4; ++ot)
#pragma unroll
      for (int nt = 0; nt < 2; ++nt)
#pragma unroll
        for (int r = 0; r < 4; ++r)
          Cs[w * 32 + nt * 16 + l16][ot * 16 + quad * 4 + r] =
              f2h(acc[ot][nt][r] + bo[ot][r]);
    __syncthreads();
    const int row = tid >> 1, seg = (tid & 1) * 32;
#pragma unroll
    for (int j = 0; j < 4; ++j)
      *(us8*)(Kb + (n0 + row) * 512 + o0 + seg + j * 8) =
          *(const us8*)&Cs[row][seg + j * 8];
  } else {  // V: emit Vt[h][d][m] directly
    ushort_t(*Cs)[72] = (ushort_t(*)[72])smem;  // [local n][o-local]
#pragma unroll
    for (int ot = 0; ot < 4; ++ot)
#pragma unroll
      for (int nt = 0; nt < 2; ++nt)
#pragma unroll
        for (int r = 0; r < 4; ++r)
          Cs[w * 32 + nt * 16 + l16][ot * 16 + quad * 4 + r] =
              f2h(acc[ot][nt][r] + bo[ot][r]);
    __syncthreads();
    const int h = blockIdx.y;
    const int d0 = blockIdx.x * 2;
    // local n row ln corresponds to n = (ln>>1)*64 + d0 + (ln&1):
    //   d = d0 + (ln&1), nh = ln>>1, m = oo*64 + nh  (oo = o-local)
#pragma unroll
    for (int t = 0; t < 4; ++t) {
      const int c = tid + t * 256;   // 0..1023 us8-chunks
      const int oo = c >> 4;         // 0..63
      const int dd = (c >> 3) & 1;
      const int g = c & 7;           // nh-group of 8
      us8 v;
#pragma unroll
      for (int j = 0; j < 8; ++j) v[j] = Cs[(g * 8 + j) * 2 + dd][oo];
      *(us8*)(Vt + h * 262144 + (d0 + dd) * 4096 + oo * 64 + g * 8) = v;
    }
  }
}

// ---------------------------------------------------------------------------
// Output projection with FUSED combine over 4 split-K partials:
// Z[n][e] = (sum_z Zp[z][n][e]) / (sum_z Lp[z][h][n]), h = e>>6.
// fp32 (N,E) out. 64o x 64n tile, 512 blocks.
// ---------------------------------------------------------------------------
__global__ __launch_bounds__(256, 2) void gemm_out(
    const ushort_t* __restrict__ Wf, const ushort_t* __restrict__ Zp,
    const float* __restrict__ Lp, const float* __restrict__ bias,
    float* __restrict__ C) {
  __shared__ __align__(16) char smem[18432];
  ushort_t(*Ws)[72] = (ushort_t(*)[72])smem;           // [64][72]
  ushort_t(*Xs)[72] = (ushort_t(*)[72])(smem + 9216);  // [64][72]

  const int tid = threadIdx.x;
  const int w = tid >> 6, lane = tid & 63, quad = lane >> 4, l16 = lane & 15;
  const int o0 = blockIdx.y * 64, n0 = blockIdx.x * 64;
  const int lr = tid >> 2, lseg = (tid & 3) * 16;

  floatx4 acc[4];
#pragma unroll
  for (int ot = 0; ot < 4; ++ot) {
    acc[ot][0] = 0.f; acc[ot][1] = 0.f; acc[ot][2] = 0.f; acc[ot][3] = 0.f;
  }

  for (int k0 = 0; k0 < EDIM; k0 += 64) {
    const int hh = k0 >> 6;
    const us8 w0 = *(const us8*)(Wf + (o0 + lr) * 512 + k0 + lseg);
    const us8 w1 = *(const us8*)(Wf + (o0 + lr) * 512 + k0 + lseg + 8);
    float za[8], zb[8];
#pragma unroll
    for (int j = 0; j < 8; ++j) { za[j] = 0.f; zb[j] = 0.f; }
    float lsum = 0.f;
#pragma unroll
    for (int zz = 0; zz < 4; ++zz) {
      const half8 zv0 =
          *(const half8*)(Zp + zz * 2097152 + (n0 + lr) * 512 + k0 + lseg);
      const half8 zv1 =
          *(const half8*)(Zp + zz * 2097152 + (n0 + lr) * 512 + k0 + lseg + 8);
#pragma unroll
      for (int j = 0; j < 8; ++j) {
        za[j] += (float)zv0[j];
        zb[j] += (float)zv1[j];
      }
      lsum += Lp[zz * 32768 + hh * 4096 + n0 + lr];
    }
    const float inv = 1.0f / lsum;
    us8 x0, x1;
#pragma unroll
    for (int j = 0; j < 8; ++j) {
      x0[j] = f2h(za[j] * inv);
      x1[j] = f2h(zb[j] * inv);
    }
    __syncthreads();
    *(us8*)&Ws[lr][lseg] = w0;
    *(us8*)&Ws[lr][lseg + 8] = w1;
    *(us8*)&Xs[lr][lseg] = x0;
    *(us8*)&Xs[lr][lseg + 8] = x1;
    __syncthreads();

    half8 a[2][4], b[2];
#pragma unroll
    for (int kh = 0; kh < 2; ++kh) {
#pragma unroll
      for (int ot = 0; ot < 4; ++ot)
        a[kh][ot] = *(const half8*)&Ws[ot * 16 + l16][kh * 32 + quad * 8];
      b[kh] = *(const half8*)&Xs[w * 16 + l16][kh * 32 + quad * 8];
    }
#pragma unroll
    for (int kh = 0; kh < 2; ++kh)
#pragma unroll
      for (int ot = 0; ot < 4; ++ot)
        acc[ot] = __builtin_amdgcn_mfma_f32_16x16x32_f16(a[kh][ot], b[kh],
                                                         acc[ot], 0, 0, 0);
  }

  __syncthreads();
  float(*Cs)[68] = (float(*)[68])smem;
#pragma unroll
  for (int ot = 0; ot < 4; ++ot) {
    floatx4 v = acc[ot];
#pragma unroll
    for (int r = 0; r < 4; ++r) v[r] += bias[o0 + ot * 16 + quad * 4 + r];
    *(floatx4*)&Cs[w * 16 + l16][ot * 16 + quad * 4] = v;
  }
  __syncthreads();
  const int row = tid >> 2, seg = (tid & 3) * 16;
#pragma unroll
  for (int j = 0; j < 4; ++j)
    *(float4*)(C + (n0 + row) * 512 + o0 + seg + j * 4) =
        *(const float4*)&Cs[row][seg + j * 4];
}

// ---------------------------------------------------------------------------
// Flash attention (R12 known-good): f16 MFMA, transposed-score, LDS-staged
// K/V, max-free softmax, rowsum via ones-MFMA, f16 Z^T partials, split-K 4.
// WIDE WAVES: each wave owns 64 q-rows (4 q-tiles), block = 256 q-rows;
// K/V fragments read once per m-pair, reused across all 4 q-tiles.
// ---------------------------------------------------------------------------
__global__ __launch_bounds__(256, 2) void attn_mfma(
    const ushort_t* __restrict__ Qb, const ushort_t* __restrict__ Kb,
    const ushort_t* __restrict__ Vt, ushort_t* __restrict__ Zp,
    float* __restrict__ Lp) {
  __shared__ __align__(16) ushort_t Ks[128][72];    // K chunk [m][d]
  __shared__ __align__(16) ushort_t Vts[64][136];   // V^T chunk [d][m]
  __shared__ __align__(16) ushort_t Ps[8][16][40];  // per (w, qt&1): P [n][32m]

  const int tid = threadIdx.x;
  const int w = tid >> 6;
  const int lane = tid & 63;
  const int quad = lane >> 4;
  const int l16 = lane & 15;
  const int h = blockIdx.y;
  const int n0 = blockIdx.x * 256;
  const int z = blockIdx.z;
  const int mbase = z * (NSEQ / 4);

  half8 qf[4][2];
#pragma unroll
  for (int qt = 0; qt < 4; ++qt) {
    const ushort_t* qsrc = Qb + h * 262144 + (n0 + w * 64 + qt * 16 + l16) * 64;
    qf[qt][0] = *(const half8*)(qsrc + quad * 8);
    qf[qt][1] = *(const half8*)(qsrc + 32 + quad * 8);
  }

  half8 ones;
#pragma unroll
  for (int j = 0; j < 8; ++j) ones[j] = (_Float16)1.0f;

  floatx4 zacc[4][4];
  floatx4 sumacc[4];
#pragma unroll
  for (int qt = 0; qt < 4; ++qt) {
    sumacc[qt][0] = 0.f; sumacc[qt][1] = 0.f;
    sumacc[qt][2] = 0.f; sumacc[qt][3] = 0.f;
#pragma unroll
    for (int dt = 0; dt < 4; ++dt) {
      zacc[qt][dt][0] = 0.f; zacc[qt][dt][1] = 0.f;
      zacc[qt][dt][2] = 0.f; zacc[qt][dt][3] = 0.f;
    }
  }

  const int kr = tid >> 2;
  const int kc = (tid & 3) << 4;
  const int vd = tid >> 2;
  const int vm = (tid & 3) << 5;

  for (int m0 = 0; m0 < NSEQ / 4; m0 += 128) {
    const ushort_t* ksrc = Kb + h * 262144 + (mbase + m0) * 64;
    const ushort_t* vsrc = Vt + h * 262144 + vd * 4096 + mbase + m0 + vm;
    us8 kst[4], vst[4];
    kst[0] = *(const us8*)(ksrc + kr * 64 + kc);
    kst[1] = *(const us8*)(ksrc + kr * 64 + kc + 8);
    kst[2] = *(const us8*)(ksrc + (64 + kr) * 64 + kc);
    kst[3] = *(const us8*)(ksrc + (64 + kr) * 64 + kc + 8);
#pragma unroll
    for (int j = 0; j < 4; ++j) vst[j] = *(const us8*)(vsrc + j * 8);

    __syncthreads();  // previous chunk's LDS reads complete
    *(us8*)&Ks[kr][kc] = kst[0];
    *(us8*)&Ks[kr][kc + 8] = kst[1];
    *(us8*)&Ks[64 + kr][kc] = kst[2];
    *(us8*)&Ks[64 + kr][kc + 8] = kst[3];
#pragma unroll
    for (int j = 0; j < 4; ++j) *(us8*)&Vts[vd][vm + j * 8] = vst[j];
    __syncthreads();

#pragma unroll
    for (int t = 0; t < 4; ++t) {
      // ---- K fragments for m-pair (mt = 2t, 2t+1); reused by all 4 qt ----
      const half8 kfA0 = *(const half8*)&Ks[(2 * t) * 16 + l16][quad * 8];
      const half8 kfA1 = *(const half8*)&Ks[(2 * t) * 16 + l16][32 + quad * 8];
      const half8 kfB0 = *(const half8*)&Ks[(2 * t + 1) * 16 + l16][quad * 8];
      const half8 kfB1 =
          *(const half8*)&Ks[(2 * t + 1) * 16 + l16][32 + quad * 8];
      // ---- V^T fragments for this m-pair; reused by all 4 qt ----
      half8 vf[4];
#pragma unroll
      for (int dt = 0; dt < 4; ++dt)
        vf[dt] = *(const half8*)&Vts[dt * 16 + l16][t * 32 + quad * 8];

#pragma unroll
      for (int qt = 0; qt < 4; ++qt) {
        floatx4 sA = {0.f, 0.f, 0.f, 0.f};
        sA = __builtin_amdgcn_mfma_f32_16x16x32_f16(kfA0, qf[qt][0], sA, 0, 0, 0);
        sA = __builtin_amdgcn_mfma_f32_16x16x32_f16(kfA1, qf[qt][1], sA, 0, 0, 0);
        floatx4 sB = {0.f, 0.f, 0.f, 0.f};
        sB = __builtin_amdgcn_mfma_f32_16x16x32_f16(kfB0, qf[qt][0], sB, 0, 0, 0);
        sB = __builtin_amdgcn_mfma_f32_16x16x32_f16(kfB1, qf[qt][1], sB, 0, 0, 0);
        union { pkhalf2 h; unsigned u; } a01, a23, b01, b23;
        a01.h = __builtin_amdgcn_cvt_pkrtz(EXP2F(sA[0]), EXP2F(sA[1]));
        a23.h = __builtin_amdgcn_cvt_pkrtz(EXP2F(sA[2]), EXP2F(sA[3]));
        b01.h = __builtin_amdgcn_cvt_pkrtz(EXP2F(sB[0]), EXP2F(sB[1]));
        b23.h = __builtin_amdgcn_cvt_pkrtz(EXP2F(sB[2]), EXP2F(sB[3]));
        ushort_t* slot = &Ps[w * 2 + (qt & 1)][l16][0];
        *(unsigned*)(slot + quad * 4) = a01.u;
        *(unsigned*)(slot + quad * 4 + 2) = a23.u;
        *(unsigned*)(slot + 16 + quad * 4) = b01.u;
        *(unsigned*)(slot + 16 + quad * 4 + 2) = b23.u;
        // same-wave LDS RAW: write->read ordered via lgkmcnt (no barrier)
        const half8 pf = *(const half8*)(slot + quad * 8);
        sumacc[qt] =
            __builtin_amdgcn_mfma_f32_16x16x32_f16(ones, pf, sumacc[qt], 0, 0, 0);
#pragma unroll
        for (int dt = 0; dt < 4; ++dt)
          zacc[qt][dt] = __builtin_amdgcn_mfma_f32_16x16x32_f16(
              vf[dt], pf, zacc[qt][dt], 0, 0, 0);
      }
    }
  }

  // ---- partial epilogue: Z^T partials as f16, row-sums fp32 ----
#pragma unroll
  for (int qt = 0; qt < 4; ++qt) {
    const int n = n0 + w * 64 + qt * 16 + l16;
    ushort_t* dst = Zp + z * 2097152 + n * EDIM + h * 64;
#pragma unroll
    for (int dt = 0; dt < 4; ++dt) {
      us4 o;
#pragma unroll
      for (int r = 0; r < 4; ++r) o[r] = f2h(zacc[qt][dt][r]);
      *(us4*)(dst + dt * 16 + quad * 4) = o;
    }
    if (quad == 0) Lp[z * 32768 + h * 4096 + n] = sumacc[qt][0];
  }
}

extern "C" void kernel_launch(void* const* d_in, const int* in_sizes, int n_in,
                              void* d_out, int out_size, void* d_ws,
                              size_t ws_size, hipStream_t stream) {
  const float* inp = (const float*)d_in[0];
  const float* WKw = (const float*)d_in[1];
  const float* WKb = (const float*)d_in[2];
  const float* WQw = (const float*)d_in[3];
  const float* WQb = (const float*)d_in[4];
  const float* WVw = (const float*)d_in[5];
  const float* WVb = (const float*)d_in[6];
  const float* WZw = (const float*)d_in[7];
  const float* WZb = (const float*)d_in[8];

  char* ws = (char*)d_ws;
  const size_t MB = 1 << 20;
  ushort_t* Xf = (ushort_t*)(ws);                        // 4MB
  ushort_t* WQf = (ushort_t*)(ws + 4 * MB);              // 512KB each
  ushort_t* WKf = (ushort_t*)(ws + 4 * MB + 512 * 1024);
  ushort_t* WVf = (ushort_t*)(ws + 5 * MB);
  ushort_t* WZf = (ushort_t*)(ws + 5 * MB + 512 * 1024);
  ushort_t* Qb = (ushort_t*)(ws + 6 * MB);    // 4MB f16 (E,N) scrambled, *C2
  ushort_t* Kb = (ushort_t*)(ws + 10 * MB);   // 4MB f16 (N,E)
  ushort_t* Vtb = (ushort_t*)(ws + 14 * MB);  // 4MB f16 [h][d][m]
  ushort_t* Zp = (ushort_t*)(ws + 18 * MB);   // 16MB: [4][4096][512] f16
  float* Lp = (float*)(ws + 34 * MB);         // 512KB: [4][8][4096]

  cast_all<<<3072, 256, 0, stream>>>(inp, Xf, WKw, WQw, WVw, WZw, WKf, WQf,
                                     WVf, WZf);

  gemm_qkv<<<dim3(NSEQ / 128, EDIM / 64, 3), 256, 0, stream>>>(
      WQf, WQb, WKf, WKb, WVf, WVb, Xf, Qb, Kb, Vtb);

  attn_mfma<<<dim3(NSEQ / 256, NHEAD, 4), 256, 0, stream>>>(Qb, Kb, Vtb, Zp,
                                                            Lp);

  gemm_out<<<dim3(NSEQ / 64, EDIM / 64), 256, 0, stream>>>(WZf, Zp, Lp, WZb,
                                                           (float*)d_out);
}

// Round 16
// 147.140 us; speedup vs baseline: 1.1799x; 1.0274x over previous
//
#include <hip/hip_runtime.h>
#include <math.h>

#define NSEQ 4096
#define EDIM 512
#define NHEAD 8
#define DHEAD 64

// LESSON (R4, R8): direct-from-global MFMA fragment loads regress vs
// LDS-staged ds_read_b128 fragments, even when perfectly coalesced/tiled.
// LESSON (R10/R14): bigger K-chunks (BK=128 gemm, 256-key attn) regress --
// LDS size/occupancy and conflicts beat barrier-amortization on this chip.
// LESSON (R11/R12): attention is LDS-traffic bound; wider per-wave q-tiles
// (64 q/wave) cut fragment re-reads 2x (53->46us). Occupancy adds nothing.
// LESSON (R13): folding fp32 casts into GEMM staging regresses ~18us.
// LESSON (R15): deleting a kernel saves ~its traffic + ~1us gap.
// R16: combine un-fused from gemm_out -- the fused version re-read the 4
// Zp planes once per o-tile (8x = 128 MB); separate combine reads them once.

typedef unsigned short ushort_t;
typedef __attribute__((ext_vector_type(8))) _Float16 half8;    // 8 f16 (4 VGPRs)
typedef __attribute__((ext_vector_type(2))) __fp16 pkhalf2;    // cvt_pkrtz out
typedef __attribute__((ext_vector_type(4))) float floatx4;     // MFMA C/D
typedef __attribute__((ext_vector_type(8))) ushort_t us8;
typedef __attribute__((ext_vector_type(4))) ushort_t us4;

#define C2SCALE 0.02254211f  // log2(e)/64, folded into Q at projection

__device__ __forceinline__ ushort_t f2h(float x) {  // RNE float->f16
  union { _Float16 h; ushort_t u; } v;
  v.h = (_Float16)x;
  return v.u;
}

#if __has_builtin(__builtin_amdgcn_exp2f)
#define EXP2F(x) __builtin_amdgcn_exp2f(x)
#else
#define EXP2F(x) exp2f(x)
#endif

// ---------------------------------------------------------------------------
// fused fp32 -> f16 cast for inp (2048 blocks) + 4 weight mats (1024 blocks)
// ---------------------------------------------------------------------------
__global__ __launch_bounds__(256) void cast_all(
    const float* __restrict__ inp, ushort_t* __restrict__ Xf,
    const float* __restrict__ w0, const float* __restrict__ w1,
    const float* __restrict__ w2, const float* __restrict__ w3,
    ushort_t* __restrict__ d0, ushort_t* __restrict__ d1,
    ushort_t* __restrict__ d2, ushort_t* __restrict__ d3) {
  const int bid = blockIdx.x;
  const float* s;
  ushort_t* d;
  int blk;
  if (bid < 2048) {
    s = inp; d = Xf; blk = bid;
  } else {
    const int seg = (bid - 2048) >> 8;
    blk = (bid - 2048) & 255;
    switch (seg) {
      case 0: s = w0; d = d0; break;
      case 1: s = w1; d = d1; break;
      case 2: s = w2; d = d2; break;
      default: s = w3; d = d3; break;
    }
  }
  const int i = (blk * 256 + threadIdx.x) * 4;
  const float4 v = *(const float4*)(s + i);
  us4 o;
  o[0] = f2h(v.x); o[1] = f2h(v.y); o[2] = f2h(v.z); o[3] = f2h(v.w);
  *(us4*)(d + i) = o;
}

// ---------------------------------------------------------------------------
// Fused QKV single-plane f16 MFMA NT GEMM, LDS-staged, BK=64, 3 blocks/CU.
// 64o x 128n tile.
// z=0: Q -> f16 (E,N) scaled by C2SCALE.   z=1: K -> f16 (N,E).
// z=2: V -> f16 Vt[h][d][m] DIRECTLY (strided n-tile; see R15).
// ---------------------------------------------------------------------------
__global__ __launch_bounds__(256, 3) void gemm_qkv(
    const ushort_t* __restrict__ WQf, const float* __restrict__ WQb,
    const ushort_t* __restrict__ WKf, const float* __restrict__ WKb,
    const ushort_t* __restrict__ WVf, const float* __restrict__ WVb,
    const ushort_t* __restrict__ Xf, ushort_t* __restrict__ Qb,
    ushort_t* __restrict__ Kb, ushort_t* __restrict__ Vt) {
  __shared__ __align__(16) char smem[27648];
  ushort_t(*Ws)[72] = (ushort_t(*)[72])smem;           // [64][72]
  ushort_t(*Xs)[72] = (ushort_t(*)[72])(smem + 9216);  // [128][72]

  const int tid = threadIdx.x;
  const int w = tid >> 6, lane = tid & 63, quad = lane >> 4, l16 = lane & 15;
  const int o0 = blockIdx.y * 64, n0 = blockIdx.x * 128, z = blockIdx.z;
  const int wr = tid >> 2, wseg = (tid & 3) * 16;  // W stage: 64 rows x 16 k
  const int xr = tid >> 1, xseg = (tid & 1) * 32;  // X stage: 128 rows x 32 k
  const int xrow = (z == 2)
                       ? ((xr >> 1) * 64 + blockIdx.x * 2 + (xr & 1))
                       : (n0 + xr);

  const ushort_t* Wf = (z == 0) ? WQf : (z == 1) ? WKf : WVf;
  const float* bias = (z == 0) ? WQb : (z == 1) ? WKb : WVb;

  floatx4 acc[4][2];
#pragma unroll
  for (int ot = 0; ot < 4; ++ot)
#pragma unroll
    for (int nt = 0; nt < 2; ++nt) {
      acc[ot][nt][0] = 0.f; acc[ot][nt][1] = 0.f;
      acc[ot][nt][2] = 0.f; acc[ot][nt][3] = 0.f;
    }

  for (int k0 = 0; k0 < EDIM; k0 += 64) {
    const us8 w0 = *(const us8*)(Wf + (o0 + wr) * 512 + k0 + wseg);
    const us8 w1 = *(const us8*)(Wf + (o0 + wr) * 512 + k0 + wseg + 8);
    us8 xv[4];
#pragma unroll
    for (int j = 0; j < 4; ++j)
      xv[j] = *(const us8*)(Xf + xrow * 512 + k0 + xseg + j * 8);
    __syncthreads();  // previous iteration's LDS reads complete
    *(us8*)&Ws[wr][wseg] = w0;
    *(us8*)&Ws[wr][wseg + 8] = w1;
#pragma unroll
    for (int j = 0; j < 4; ++j) *(us8*)&Xs[xr][xseg + j * 8] = xv[j];
    __syncthreads();

    half8 a[2][4], b[2][2];
#pragma unroll
    for (int kh = 0; kh < 2; ++kh) {
#pragma unroll
      for (int ot = 0; ot < 4; ++ot)
        a[kh][ot] = *(const half8*)&Ws[ot * 16 + l16][kh * 32 + quad * 8];
#pragma unroll
      for (int nt = 0; nt < 2; ++nt)
        b[kh][nt] =
            *(const half8*)&Xs[w * 32 + nt * 16 + l16][kh * 32 + quad * 8];
    }
#pragma unroll
    for (int kh = 0; kh < 2; ++kh)
#pragma unroll
      for (int ot = 0; ot < 4; ++ot)
#pragma unroll
        for (int nt = 0; nt < 2; ++nt)
          acc[ot][nt] = __builtin_amdgcn_mfma_f32_16x16x32_f16(
              a[kh][ot], b[kh][nt], acc[ot][nt], 0, 0, 0);
  }

  __syncthreads();  // staging reads done; smem reused for epilogue
  float bo[4][4];
#pragma unroll
  for (int ot = 0; ot < 4; ++ot)
#pragma unroll
    for (int r = 0; r < 4; ++r)
      bo[ot][r] = bias[o0 + ot * 16 + quad * 4 + r];

  if (z == 0) {  // Q: f16 (E,N), scaled
    ushort_t(*Cs)[136] = (ushort_t(*)[136])smem;
#pragma unroll
    for (int ot = 0; ot < 4; ++ot)
#pragma unroll
      for (int nt = 0; nt < 2; ++nt)
#pragma unroll
        for (int r = 0; r < 4; ++r)
          Cs[ot * 16 + quad * 4 + r][w * 32 + nt * 16 + l16] =
              f2h((acc[ot][nt][r] + bo[ot][r]) * C2SCALE);
    __syncthreads();
    const int row = tid >> 2, seg = (tid & 3) * 32;
#pragma unroll
    for (int j = 0; j < 4; ++j)
      *(us8*)(Qb + (o0 + row) * 4096 + n0 + seg + j * 8) =
          *(const us8*)&Cs[row][seg + j * 8];
  } else if (z == 1) {  // K: f16 (N,E)
    ushort_t(*Cs)[72] = (ushort_t(*)[72])smem;
#pragma unroll
    for (int ot = 0; ot < 4; ++ot)
#pragma unroll
      for (int nt = 0; nt < 2; ++nt)
#pragma unroll
        for (int r = 0; r < 4; ++r)
          Cs[w * 32 + nt * 16 + l16][ot * 16 + quad * 4 + r] =
              f2h(acc[ot][nt][r] + bo[ot][r]);
    __syncthreads();
    const int row = tid >> 1, seg = (tid & 1) * 32;
#pragma unroll
    for (int j = 0; j < 4; ++j)
      *(us8*)(Kb + (n0 + row) * 512 + o0 + seg + j * 8) =
          *(const us8*)&Cs[row][seg + j * 8];
  } else {  // V: emit Vt[h][d][m] directly
    ushort_t(*Cs)[72] = (ushort_t(*)[72])smem;  // [local n][o-local]
#pragma unroll
    for (int ot = 0; ot < 4; ++ot)
#pragma unroll
      for (int nt = 0; nt < 2; ++nt)
#pragma unroll
        for (int r = 0; r < 4; ++r)
          Cs[w * 32 + nt * 16 + l16][ot * 16 + quad * 4 + r] =
              f2h(acc[ot][nt][r] + bo[ot][r]);
    __syncthreads();
    const int h = blockIdx.y;
    const int d0 = blockIdx.x * 2;
#pragma unroll
    for (int t = 0; t < 4; ++t) {
      const int c = tid + t * 256;   // 0..1023 us8-chunks
      const int oo = c >> 4;         // 0..63
      const int dd = (c >> 3) & 1;
      const int g = c & 7;           // nh-group of 8
      us8 v;
#pragma unroll
      for (int j = 0; j < 8; ++j) v[j] = Cs[(g * 8 + j) * 2 + dd][oo];
      *(us8*)(Vt + h * 262144 + (d0 + dd) * 4096 + oo * 64 + g * 8) = v;
    }
  }
}

// ---------------------------------------------------------------------------
// combine: Zf[n][e] = (sum_z Zp[z][n][e]) / (sum_z Lp[z][h][n]), f16 out.
// Reads the 4 Zp planes ONCE (vs 8x when fused into gemm_out).
// ---------------------------------------------------------------------------
__global__ __launch_bounds__(256) void combine(const ushort_t* __restrict__ Zp,
                                               const float* __restrict__ Lp,
                                               ushort_t* __restrict__ Zf) {
  const int base = (blockIdx.x * 256 + threadIdx.x) * 8;
  const int n = base >> 9, e = base & 511, h = e >> 6;
  float lsum = 0.f;
  float va[8];
#pragma unroll
  for (int j = 0; j < 8; ++j) va[j] = 0.f;
#pragma unroll
  for (int zz = 0; zz < 4; ++zz) {
    const half8 v = *(const half8*)(Zp + zz * 2097152 + base);
#pragma unroll
    for (int j = 0; j < 8; ++j) va[j] += (float)v[j];
    lsum += Lp[zz * 32768 + h * 4096 + n];
  }
  const float inv = 1.0f / lsum;
  us8 o;
#pragma unroll
  for (int j = 0; j < 8; ++j) o[j] = f2h(va[j] * inv);
  *(us8*)(Zf + base) = o;
}

// ---------------------------------------------------------------------------
// Output projection: f16 W and Zf from LDS, fp32 (N,E) out. BK=64,
// 64o x 64n tile, 512 blocks.
// ---------------------------------------------------------------------------
__global__ __launch_bounds__(256, 2) void gemm_out(
    const ushort_t* __restrict__ Wf, const ushort_t* __restrict__ Zf,
    const float* __restrict__ bias, float* __restrict__ C) {
  __shared__ __align__(16) char smem[18432];
  ushort_t(*Ws)[72] = (ushort_t(*)[72])smem;           // [64][72]
  ushort_t(*Xs)[72] = (ushort_t(*)[72])(smem + 9216);  // [64][72]

  const int tid = threadIdx.x;
  const int w = tid >> 6, lane = tid & 63, quad = lane >> 4, l16 = lane & 15;
  const int o0 = blockIdx.y * 64, n0 = blockIdx.x * 64;
  const int lr = tid >> 2, lseg = (tid & 3) * 16;

  floatx4 acc[4];
#pragma unroll
  for (int ot = 0; ot < 4; ++ot) {
    acc[ot][0] = 0.f; acc[ot][1] = 0.f; acc[ot][2] = 0.f; acc[ot][3] = 0.f;
  }

  for (int k0 = 0; k0 < EDIM; k0 += 64) {
    const us8 w0 = *(const us8*)(Wf + (o0 + lr) * 512 + k0 + lseg);
    const us8 w1 = *(const us8*)(Wf + (o0 + lr) * 512 + k0 + lseg + 8);
    const us8 x0 = *(const us8*)(Zf + (n0 + lr) * 512 + k0 + lseg);
    const us8 x1 = *(const us8*)(Zf + (n0 + lr) * 512 + k0 + lseg + 8);
    __syncthreads();
    *(us8*)&Ws[lr][lseg] = w0;
    *(us8*)&Ws[lr][lseg + 8] = w1;
    *(us8*)&Xs[lr][lseg] = x0;
    *(us8*)&Xs[lr][lseg + 8] = x1;
    __syncthreads();

    half8 a[2][4], b[2];
#pragma unroll
    for (int kh = 0; kh < 2; ++kh) {
#pragma unroll
      for (int ot = 0; ot < 4; ++ot)
        a[kh][ot] = *(const half8*)&Ws[ot * 16 + l16][kh * 32 + quad * 8];
      b[kh] = *(const half8*)&Xs[w * 16 + l16][kh * 32 + quad * 8];
    }
#pragma unroll
    for (int kh = 0; kh < 2; ++kh)
#pragma unroll
      for (int ot = 0; ot < 4; ++ot)
        acc[ot] = __builtin_amdgcn_mfma_f32_16x16x32_f16(a[kh][ot], b[kh],
                                                         acc[ot], 0, 0, 0);
  }

  __syncthreads();
  float(*Cs)[68] = (float(*)[68])smem;
#pragma unroll
  for (int ot = 0; ot < 4; ++ot) {
    floatx4 v = acc[ot];
#pragma unroll
    for (int r = 0; r < 4; ++r) v[r] += bias[o0 + ot * 16 + quad * 4 + r];
    *(floatx4*)&Cs[w * 16 + l16][ot * 16 + quad * 4] = v;
  }
  __syncthreads();
  const int row = tid >> 2, seg = (tid & 3) * 16;
#pragma unroll
  for (int j = 0; j < 4; ++j)
    *(float4*)(C + (n0 + row) * 512 + o0 + seg + j * 4) =
        *(const float4*)&Cs[row][seg + j * 4];
}

// ---------------------------------------------------------------------------
// Flash attention (R12/R15 known-good): f16 MFMA, transposed-score,
// LDS-staged K/V, max-free softmax, rowsum via ones-MFMA, f16 Z^T partials,
// split-K 4. WIDE WAVES: each wave owns 64 q-rows (4 q-tiles), block = 256
// q-rows; K/V fragments read once per m-pair, reused across all 4 q-tiles.
// ---------------------------------------------------------------------------
__global__ __launch_bounds__(256, 2) void attn_mfma(
    const ushort_t* __restrict__ Qb, const ushort_t* __restrict__ Kb,
    const ushort_t* __restrict__ Vt, ushort_t* __restrict__ Zp,
    float* __restrict__ Lp) {
  __shared__ __align__(16) ushort_t Ks[128][72];    // K chunk [m][d]
  __shared__ __align__(16) ushort_t Vts[64][136];   // V^T chunk [d][m]
  __shared__ __align__(16) ushort_t Ps[8][16][40];  // per (w, qt&1): P [n][32m]

  const int tid = threadIdx.x;
  const int w = tid >> 6;
  const int lane = tid & 63;
  const int quad = lane >> 4;
  const int l16 = lane & 15;
  const int h = blockIdx.y;
  const int n0 = blockIdx.x * 256;
  const int z = blockIdx.z;
  const int mbase = z * (NSEQ / 4);

  half8 qf[4][2];
#pragma unroll
  for (int qt = 0; qt < 4; ++qt) {
    const ushort_t* qsrc = Qb + h * 262144 + (n0 + w * 64 + qt * 16 + l16) * 64;
    qf[qt][0] = *(const half8*)(qsrc + quad * 8);
    qf[qt][1] = *(const half8*)(qsrc + 32 + quad * 8);
  }

  half8 ones;
#pragma unroll
  for (int j = 0; j < 8; ++j) ones[j] = (_Float16)1.0f;

  floatx4 zacc[4][4];
  floatx4 sumacc[4];
#pragma unroll
  for (int qt = 0; qt < 4; ++qt) {
    sumacc[qt][0] = 0.f; sumacc[qt][1] = 0.f;
    sumacc[qt][2] = 0.f; sumacc[qt][3] = 0.f;
#pragma unroll
    for (int dt = 0; dt < 4; ++dt) {
      zacc[qt][dt][0] = 0.f; zacc[qt][dt][1] = 0.f;
      zacc[qt][dt][2] = 0.f; zacc[qt][dt][3] = 0.f;
    }
  }

  const int kr = tid >> 2;
  const int kc = (tid & 3) << 4;
  const int vd = tid >> 2;
  const int vm = (tid & 3) << 5;

  for (int m0 = 0; m0 < NSEQ / 4; m0 += 128) {
    const ushort_t* ksrc = Kb + h * 262144 + (mbase + m0) * 64;
    const ushort_t* vsrc = Vt + h * 262144 + vd * 4096 + mbase + m0 + vm;
    us8 kst[4], vst[4];
    kst[0] = *(const us8*)(ksrc + kr * 64 + kc);
    kst[1] = *(const us8*)(ksrc + kr * 64 + kc + 8);
    kst[2] = *(const us8*)(ksrc + (64 + kr) * 64 + kc);
    kst[3] = *(const us8*)(ksrc + (64 + kr) * 64 + kc + 8);
#pragma unroll
    for (int j = 0; j < 4; ++j) vst[j] = *(const us8*)(vsrc + j * 8);

    __syncthreads();  // previous chunk's LDS reads complete
    *(us8*)&Ks[kr][kc] = kst[0];
    *(us8*)&Ks[kr][kc + 8] = kst[1];
    *(us8*)&Ks[64 + kr][kc] = kst[2];
    *(us8*)&Ks[64 + kr][kc + 8] = kst[3];
#pragma unroll
    for (int j = 0; j < 4; ++j) *(us8*)&Vts[vd][vm + j * 8] = vst[j];
    __syncthreads();

#pragma unroll
    for (int t = 0; t < 4; ++t) {
      // ---- K fragments for m-pair (mt = 2t, 2t+1); reused by all 4 qt ----
      const half8 kfA0 = *(const half8*)&Ks[(2 * t) * 16 + l16][quad * 8];
      const half8 kfA1 = *(const half8*)&Ks[(2 * t) * 16 + l16][32 + quad * 8];
      const half8 kfB0 = *(const half8*)&Ks[(2 * t + 1) * 16 + l16][quad * 8];
      const half8 kfB1 =
          *(const half8*)&Ks[(2 * t + 1) * 16 + l16][32 + quad * 8];
      // ---- V^T fragments for this m-pair; reused by all 4 qt ----
      half8 vf[4];
#pragma unroll
      for (int dt = 0; dt < 4; ++dt)
        vf[dt] = *(const half8*)&Vts[dt * 16 + l16][t * 32 + quad * 8];

#pragma unroll
      for (int qt = 0; qt < 4; ++qt) {
        floatx4 sA = {0.f, 0.f, 0.f, 0.f};
        sA = __builtin_amdgcn_mfma_f32_16x16x32_f16(kfA0, qf[qt][0], sA, 0, 0, 0);
        sA = __builtin_amdgcn_mfma_f32_16x16x32_f16(kfA1, qf[qt][1], sA, 0, 0, 0);
        floatx4 sB = {0.f, 0.f, 0.f, 0.f};
        sB = __builtin_amdgcn_mfma_f32_16x16x32_f16(kfB0, qf[qt][0], sB, 0, 0, 0);
        sB = __builtin_amdgcn_mfma_f32_16x16x32_f16(kfB1, qf[qt][1], sB, 0, 0, 0);
        union { pkhalf2 h; unsigned u; } a01, a23, b01, b23;
        a01.h = __builtin_amdgcn_cvt_pkrtz(EXP2F(sA[0]), EXP2F(sA[1]));
        a23.h = __builtin_amdgcn_cvt_pkrtz(EXP2F(sA[2]), EXP2F(sA[3]));
        b01.h = __builtin_amdgcn_cvt_pkrtz(EXP2F(sB[0]), EXP2F(sB[1]));
        b23.h = __builtin_amdgcn_cvt_pkrtz(EXP2F(sB[2]), EXP2F(sB[3]));
        ushort_t* slot = &Ps[w * 2 + (qt & 1)][l16][0];
        *(unsigned*)(slot + quad * 4) = a01.u;
        *(unsigned*)(slot + quad * 4 + 2) = a23.u;
        *(unsigned*)(slot + 16 + quad * 4) = b01.u;
        *(unsigned*)(slot + 16 + quad * 4 + 2) = b23.u;
        // same-wave LDS RAW: write->read ordered via lgkmcnt (no barrier)
        const half8 pf = *(const half8*)(slot + quad * 8);
        sumacc[qt] =
            __builtin_amdgcn_mfma_f32_16x16x32_f16(ones, pf, sumacc[qt], 0, 0, 0);
#pragma unroll
        for (int dt = 0; dt < 4; ++dt)
          zacc[qt][dt] = __builtin_amdgcn_mfma_f32_16x16x32_f16(
              vf[dt], pf, zacc[qt][dt], 0, 0, 0);
      }
    }
  }

  // ---- partial epilogue: Z^T partials as f16, row-sums fp32 ----
#pragma unroll
  for (int qt = 0; qt < 4; ++qt) {
    const int n = n0 + w * 64 + qt * 16 + l16;
    ushort_t* dst = Zp + z * 2097152 + n * EDIM + h * 64;
#pragma unroll
    for (int dt = 0; dt < 4; ++dt) {
      us4 o;
#pragma unroll
      for (int r = 0; r < 4; ++r) o[r] = f2h(zacc[qt][dt][r]);
      *(us4*)(dst + dt * 16 + quad * 4) = o;
    }
    if (quad == 0) Lp[z * 32768 + h * 4096 + n] = sumacc[qt][0];
  }
}

extern "C" void kernel_launch(void* const* d_in, const int* in_sizes, int n_in,
                              void* d_out, int out_size, void* d_ws,
                              size_t ws_size, hipStream_t stream) {
  const float* inp = (const float*)d_in[0];
  const float* WKw = (const float*)d_in[1];
  const float* WKb = (const float*)d_in[2];
  const float* WQw = (const float*)d_in[3];
  const float* WQb = (const float*)d_in[4];
  const float* WVw = (const float*)d_in[5];
  const float* WVb = (const float*)d_in[6];
  const float* WZw = (const float*)d_in[7];
  const float* WZb = (const float*)d_in[8];

  char* ws = (char*)d_ws;
  const size_t MB = 1 << 20;
  ushort_t* Xf = (ushort_t*)(ws);                        // 4MB; Zf after attn
  ushort_t* WQf = (ushort_t*)(ws + 4 * MB);              // 512KB each
  ushort_t* WKf = (ushort_t*)(ws + 4 * MB + 512 * 1024);
  ushort_t* WVf = (ushort_t*)(ws + 5 * MB);
  ushort_t* WZf = (ushort_t*)(ws + 5 * MB + 512 * 1024);
  ushort_t* Qb = (ushort_t*)(ws + 6 * MB);    // 4MB f16 (E,N) scrambled, *C2
  ushort_t* Kb = (ushort_t*)(ws + 10 * MB);   // 4MB f16 (N,E)
  ushort_t* Vtb = (ushort_t*)(ws + 14 * MB);  // 4MB f16 [h][d][m]
  ushort_t* Zp = (ushort_t*)(ws + 18 * MB);   // 16MB: [4][4096][512] f16
  float* Lp = (float*)(ws + 34 * MB);         // 512KB: [4][8][4096]

  cast_all<<<3072, 256, 0, stream>>>(inp, Xf, WKw, WQw, WVw, WZw, WKf, WQf,
                                     WVf, WZf);

  gemm_qkv<<<dim3(NSEQ / 128, EDIM / 64, 3), 256, 0, stream>>>(
      WQf, WQb, WKf, WKb, WVf, WVb, Xf, Qb, Kb, Vtb);

  attn_mfma<<<dim3(NSEQ / 256, NHEAD, 4), 256, 0, stream>>>(Qb, Kb, Vtb, Zp,
                                                            Lp);

  combine<<<1024, 256, 0, stream>>>(Zp, Lp, Xf);  // Xf reused as Zf

  gemm_out<<<dim3(NSEQ / 64, EDIM / 64), 256, 0, stream>>>(WZf, Xf, WZb,
                                                           (float*)d_out);
}

// Round 17
// 145.656 us; speedup vs baseline: 1.1919x; 1.0102x over previous
//
#include <hip/hip_runtime.h>
#include <math.h>

#define NSEQ 4096
#define EDIM 512
#define NHEAD 8
#define DHEAD 64

// LESSON (R4, R8): direct-from-global MFMA fragment loads regress vs
// LDS-staged ds_read_b128 fragments, even when perfectly coalesced/tiled.
// LESSON (R10/R14): bigger K-chunks (BK=128 gemm, 256-key attn) regress --
// LDS size/occupancy and conflicts beat barrier-amortization on this chip.
// LESSON (R11/R12): attention is LDS-traffic bound; wider per-wave q-tiles
// (64 q/wave) cut fragment re-reads 2x (53->46us). Occupancy adds nothing.
// LESSON (R13): folding fp32 casts into GEMM staging regresses ~18us.
// LESSON (R15/R16): kernel deletion and traffic de-duplication pay exactly
// their traffic cost (~4us each). Harness re-poison (~45us fillBuffer on the
// same stream) is a fixed cost outside our control.
// R17: rowsum via VALU adds + 2 shfl_xor instead of ones-MFMA (drops 5 of 25
// MFMAs/qt-iter from the dependent chain; absmax ~7e-4 per R8 measurement).

typedef unsigned short ushort_t;
typedef __attribute__((ext_vector_type(8))) _Float16 half8;    // 8 f16 (4 VGPRs)
typedef __attribute__((ext_vector_type(2))) __fp16 pkhalf2;    // cvt_pkrtz out
typedef __attribute__((ext_vector_type(4))) float floatx4;     // MFMA C/D
typedef __attribute__((ext_vector_type(8))) ushort_t us8;
typedef __attribute__((ext_vector_type(4))) ushort_t us4;

#define C2SCALE 0.02254211f  // log2(e)/64, folded into Q at projection

__device__ __forceinline__ ushort_t f2h(float x) {  // RNE float->f16
  union { _Float16 h; ushort_t u; } v;
  v.h = (_Float16)x;
  return v.u;
}

#if __has_builtin(__builtin_amdgcn_exp2f)
#define EXP2F(x) __builtin_amdgcn_exp2f(x)
#else
#define EXP2F(x) exp2f(x)
#endif

// ---------------------------------------------------------------------------
// fused fp32 -> f16 cast for inp (2048 blocks) + 4 weight mats (1024 blocks)
// ---------------------------------------------------------------------------
__global__ __launch_bounds__(256) void cast_all(
    const float* __restrict__ inp, ushort_t* __restrict__ Xf,
    const float* __restrict__ w0, const float* __restrict__ w1,
    const float* __restrict__ w2, const float* __restrict__ w3,
    ushort_t* __restrict__ d0, ushort_t* __restrict__ d1,
    ushort_t* __restrict__ d2, ushort_t* __restrict__ d3) {
  const int bid = blockIdx.x;
  const float* s;
  ushort_t* d;
  int blk;
  if (bid < 2048) {
    s = inp; d = Xf; blk = bid;
  } else {
    const int seg = (bid - 2048) >> 8;
    blk = (bid - 2048) & 255;
    switch (seg) {
      case 0: s = w0; d = d0; break;
      case 1: s = w1; d = d1; break;
      case 2: s = w2; d = d2; break;
      default: s = w3; d = d3; break;
    }
  }
  const int i = (blk * 256 + threadIdx.x) * 4;
  const float4 v = *(const float4*)(s + i);
  us4 o;
  o[0] = f2h(v.x); o[1] = f2h(v.y); o[2] = f2h(v.z); o[3] = f2h(v.w);
  *(us4*)(d + i) = o;
}

// ---------------------------------------------------------------------------
// Fused QKV single-plane f16 MFMA NT GEMM, LDS-staged, BK=64, 3 blocks/CU.
// 64o x 128n tile.
// z=0: Q -> f16 (E,N) scaled by C2SCALE.   z=1: K -> f16 (N,E).
// z=2: V -> f16 Vt[h][d][m] DIRECTLY (strided n-tile; see R15).
// ---------------------------------------------------------------------------
__global__ __launch_bounds__(256, 3) void gemm_qkv(
    const ushort_t* __restrict__ WQf, const float* __restrict__ WQb,
    const ushort_t* __restrict__ WKf, const float* __restrict__ WKb,
    const ushort_t* __restrict__ WVf, const float* __restrict__ WVb,
    const ushort_t* __restrict__ Xf, ushort_t* __restrict__ Qb,
    ushort_t* __restrict__ Kb, ushort_t* __restrict__ Vt) {
  __shared__ __align__(16) char smem[27648];
  ushort_t(*Ws)[72] = (ushort_t(*)[72])smem;           // [64][72]
  ushort_t(*Xs)[72] = (ushort_t(*)[72])(smem + 9216);  // [128][72]

  const int tid = threadIdx.x;
  const int w = tid >> 6, lane = tid & 63, quad = lane >> 4, l16 = lane & 15;
  const int o0 = blockIdx.y * 64, n0 = blockIdx.x * 128, z = blockIdx.z;
  const int wr = tid >> 2, wseg = (tid & 3) * 16;  // W stage: 64 rows x 16 k
  const int xr = tid >> 1, xseg = (tid & 1) * 32;  // X stage: 128 rows x 32 k
  const int xrow = (z == 2)
                       ? ((xr >> 1) * 64 + blockIdx.x * 2 + (xr & 1))
                       : (n0 + xr);

  const ushort_t* Wf = (z == 0) ? WQf : (z == 1) ? WKf : WVf;
  const float* bias = (z == 0) ? WQb : (z == 1) ? WKb : WVb;

  floatx4 acc[4][2];
#pragma unroll
  for (int ot = 0; ot < 4; ++ot)
#pragma unroll
    for (int nt = 0; nt < 2; ++nt) {
      acc[ot][nt][0] = 0.f; acc[ot][nt][1] = 0.f;
      acc[ot][nt][2] = 0.f; acc[ot][nt][3] = 0.f;
    }

  for (int k0 = 0; k0 < EDIM; k0 += 64) {
    const us8 w0 = *(const us8*)(Wf + (o0 + wr) * 512 + k0 + wseg);
    const us8 w1 = *(const us8*)(Wf + (o0 + wr) * 512 + k0 + wseg + 8);
    us8 xv[4];
#pragma unroll
    for (int j = 0; j < 4; ++j)
      xv[j] = *(const us8*)(Xf + xrow * 512 + k0 + xseg + j * 8);
    __syncthreads();  // previous iteration's LDS reads complete
    *(us8*)&Ws[wr][wseg] = w0;
    *(us8*)&Ws[wr][wseg + 8] = w1;
#pragma unroll
    for (int j = 0; j < 4; ++j) *(us8*)&Xs[xr][xseg + j * 8] = xv[j];
    __syncthreads();

    half8 a[2][4], b[2][2];
#pragma unroll
    for (int kh = 0; kh < 2; ++kh) {
#pragma unroll
      for (int ot = 0; ot < 4; ++ot)
        a[kh][ot] = *(const half8*)&Ws[ot * 16 + l16][kh * 32 + quad * 8];
#pragma unroll
      for (int nt = 0; nt < 2; ++nt)
        b[kh][nt] =
            *(const half8*)&Xs[w * 32 + nt * 16 + l16][kh * 32 + quad * 8];
    }
#pragma unroll
    for (int kh = 0; kh < 2; ++kh)
#pragma unroll
      for (int ot = 0; ot < 4; ++ot)
#pragma unroll
        for (int nt = 0; nt < 2; ++nt)
          acc[ot][nt] = __builtin_amdgcn_mfma_f32_16x16x32_f16(
              a[kh][ot], b[kh][nt], acc[ot][nt], 0, 0, 0);
  }

  __syncthreads();  // staging reads done; smem reused for epilogue
  float bo[4][4];
#pragma unroll
  for (int ot = 0; ot < 4; ++ot)
#pragma unroll
    for (int r = 0; r < 4; ++r)
      bo[ot][r] = bias[o0 + ot * 16 + quad * 4 + r];

  if (z == 0) {  // Q: f16 (E,N), scaled
    ushort_t(*Cs)[136] = (ushort_t(*)[136])smem;
#pragma unroll
    for (int ot = 0; ot < 4; ++ot)
#pragma unroll
      for (int nt = 0; nt < 2; ++nt)
#pragma unroll
        for (int r = 0; r < 4; ++r)
          Cs[ot * 16 + quad * 4 + r][w * 32 + nt * 16 + l16] =
              f2h((acc[ot][nt][r] + bo[ot][r]) * C2SCALE);
    __syncthreads();
    const int row = tid >> 2, seg = (tid & 3) * 32;
#pragma unroll
    for (int j = 0; j < 4; ++j)
      *(us8*)(Qb + (o0 + row) * 4096 + n0 + seg + j * 8) =
          *(const us8*)&Cs[row][seg + j * 8];
  } else if (z == 1) {  // K: f16 (N,E)
    ushort_t(*Cs)[72] = (ushort_t(*)[72])smem;
#pragma unroll
    for (int ot = 0; ot < 4; ++ot)
#pragma unroll
      for (int nt = 0; nt < 2; ++nt)
#pragma unroll
        for (int r = 0; r < 4; ++r)
          Cs[w * 32 + nt * 16 + l16][ot * 16 + quad * 4 + r] =
              f2h(acc[ot][nt][r] + bo[ot][r]);
    __syncthreads();
    const int row = tid >> 1, seg = (tid & 1) * 32;
#pragma unroll
    for (int j = 0; j < 4; ++j)
      *(us8*)(Kb + (n0 + row) * 512 + o0 + seg + j * 8) =
          *(const us8*)&Cs[row][seg + j * 8];
  } else {  // V: emit Vt[h][d][m] directly
    ushort_t(*Cs)[72] = (ushort_t(*)[72])smem;  // [local n][o-local]
#pragma unroll
    for (int ot = 0; ot < 4; ++ot)
#pragma unroll
      for (int nt = 0; nt < 2; ++nt)
#pragma unroll
        for (int r = 0; r < 4; ++r)
          Cs[w * 32 + nt * 16 + l16][ot * 16 + quad * 4 + r] =
              f2h(acc[ot][nt][r] + bo[ot][r]);
    __syncthreads();
    const int h = blockIdx.y;
    const int d0 = blockIdx.x * 2;
#pragma unroll
    for (int t = 0; t < 4; ++t) {
      const int c = tid + t * 256;   // 0..1023 us8-chunks
      const int oo = c >> 4;         // 0..63
      const int dd = (c >> 3) & 1;
      const int g = c & 7;           // nh-group of 8
      us8 v;
#pragma unroll
      for (int j = 0; j < 8; ++j) v[j] = Cs[(g * 8 + j) * 2 + dd][oo];
      *(us8*)(Vt + h * 262144 + (d0 + dd) * 4096 + oo * 64 + g * 8) = v;
    }
  }
}

// ---------------------------------------------------------------------------
// combine: Zf[n][e] = (sum_z Zp[z][n][e]) / (sum_z Lp[z][h][n]), f16 out.
// Reads the 4 Zp planes ONCE (vs 8x when fused into gemm_out).
// ---------------------------------------------------------------------------
__global__ __launch_bounds__(256) void combine(const ushort_t* __restrict__ Zp,
                                               const float* __restrict__ Lp,
                                               ushort_t* __restrict__ Zf) {
  const int base = (blockIdx.x * 256 + threadIdx.x) * 8;
  const int n = base >> 9, e = base & 511, h = e >> 6;
  float lsum = 0.f;
  float va[8];
#pragma unroll
  for (int j = 0; j < 8; ++j) va[j] = 0.f;
#pragma unroll
  for (int zz = 0; zz < 4; ++zz) {
    const half8 v = *(const half8*)(Zp + zz * 2097152 + base);
#pragma unroll
    for (int j = 0; j < 8; ++j) va[j] += (float)v[j];
    lsum += Lp[zz * 32768 + h * 4096 + n];
  }
  const float inv = 1.0f / lsum;
  us8 o;
#pragma unroll
  for (int j = 0; j < 8; ++j) o[j] = f2h(va[j] * inv);
  *(us8*)(Zf + base) = o;
}

// ---------------------------------------------------------------------------
// Output projection: f16 W and Zf from LDS, fp32 (N,E) out. BK=64,
// 64o x 64n tile, 512 blocks.
// ---------------------------------------------------------------------------
__global__ __launch_bounds__(256, 2) void gemm_out(
    const ushort_t* __restrict__ Wf, const ushort_t* __restrict__ Zf,
    const float* __restrict__ bias, float* __restrict__ C) {
  __shared__ __align__(16) char smem[18432];
  ushort_t(*Ws)[72] = (ushort_t(*)[72])smem;           // [64][72]
  ushort_t(*Xs)[72] = (ushort_t(*)[72])(smem + 9216);  // [64][72]

  const int tid = threadIdx.x;
  const int w = tid >> 6, lane = tid & 63, quad = lane >> 4, l16 = lane & 15;
  const int o0 = blockIdx.y * 64, n0 = blockIdx.x * 64;
  const int lr = tid >> 2, lseg = (tid & 3) * 16;

  floatx4 acc[4];
#pragma unroll
  for (int ot = 0; ot < 4; ++ot) {
    acc[ot][0] = 0.f; acc[ot][1] = 0.f; acc[ot][2] = 0.f; acc[ot][3] = 0.f;
  }

  for (int k0 = 0; k0 < EDIM; k0 += 64) {
    const us8 w0 = *(const us8*)(Wf + (o0 + lr) * 512 + k0 + lseg);
    const us8 w1 = *(const us8*)(Wf + (o0 + lr) * 512 + k0 + lseg + 8);
    const us8 x0 = *(const us8*)(Zf + (n0 + lr) * 512 + k0 + lseg);
    const us8 x1 = *(const us8*)(Zf + (n0 + lr) * 512 + k0 + lseg + 8);
    __syncthreads();
    *(us8*)&Ws[lr][lseg] = w0;
    *(us8*)&Ws[lr][lseg + 8] = w1;
    *(us8*)&Xs[lr][lseg] = x0;
    *(us8*)&Xs[lr][lseg + 8] = x1;
    __syncthreads();

    half8 a[2][4], b[2];
#pragma unroll
    for (int kh = 0; kh < 2; ++kh) {
#pragma unroll
      for (int ot = 0; ot < 4; ++ot)
        a[kh][ot] = *(const half8*)&Ws[ot * 16 + l16][kh * 32 + quad * 8];
      b[kh] = *(const half8*)&Xs[w * 16 + l16][kh * 32 + quad * 8];
    }
#pragma unroll
    for (int kh = 0; kh < 2; ++kh)
#pragma unroll
      for (int ot = 0; ot < 4; ++ot)
        acc[ot] = __builtin_amdgcn_mfma_f32_16x16x32_f16(a[kh][ot], b[kh],
                                                         acc[ot], 0, 0, 0);
  }

  __syncthreads();
  float(*Cs)[68] = (float(*)[68])smem;
#pragma unroll
  for (int ot = 0; ot < 4; ++ot) {
    floatx4 v = acc[ot];
#pragma unroll
    for (int r = 0; r < 4; ++r) v[r] += bias[o0 + ot * 16 + quad * 4 + r];
    *(floatx4*)&Cs[w * 16 + l16][ot * 16 + quad * 4] = v;
  }
  __syncthreads();
  const int row = tid >> 2, seg = (tid & 3) * 16;
#pragma unroll
  for (int j = 0; j < 4; ++j)
    *(float4*)(C + (n0 + row) * 512 + o0 + seg + j * 4) =
        *(const float4*)&Cs[row][seg + j * 4];
}

// ---------------------------------------------------------------------------
// Flash attention: f16 MFMA, transposed-score, LDS-staged K/V, max-free
// softmax, f16 Z^T partials, split-K 4. WIDE WAVES: each wave owns 64 q-rows
// (4 q-tiles), block = 256 q-rows; K/V fragments read once per m-pair,
// reused across all 4 q-tiles. R17: rowsum via lane-local VALU adds
// (lane (quad,l16) holds m%16 in [quad*4,quad*4+4)) + 2 shfl_xor epilogue.
// ---------------------------------------------------------------------------
__global__ __launch_bounds__(256, 2) void attn_mfma(
    const ushort_t* __restrict__ Qb, const ushort_t* __restrict__ Kb,
    const ushort_t* __restrict__ Vt, ushort_t* __restrict__ Zp,
    float* __restrict__ Lp) {
  __shared__ __align__(16) ushort_t Ks[128][72];    // K chunk [m][d]
  __shared__ __align__(16) ushort_t Vts[64][136];   // V^T chunk [d][m]
  __shared__ __align__(16) ushort_t Ps[8][16][40];  // per (w, qt&1): P [n][32m]

  const int tid = threadIdx.x;
  const int w = tid >> 6;
  const int lane = tid & 63;
  const int quad = lane >> 4;
  const int l16 = lane & 15;
  const int h = blockIdx.y;
  const int n0 = blockIdx.x * 256;
  const int z = blockIdx.z;
  const int mbase = z * (NSEQ / 4);

  half8 qf[4][2];
#pragma unroll
  for (int qt = 0; qt < 4; ++qt) {
    const ushort_t* qsrc = Qb + h * 262144 + (n0 + w * 64 + qt * 16 + l16) * 64;
    qf[qt][0] = *(const half8*)(qsrc + quad * 8);
    qf[qt][1] = *(const half8*)(qsrc + 32 + quad * 8);
  }

  floatx4 zacc[4][4];
  float sl[4] = {0.f, 0.f, 0.f, 0.f};
#pragma unroll
  for (int qt = 0; qt < 4; ++qt)
#pragma unroll
    for (int dt = 0; dt < 4; ++dt) {
      zacc[qt][dt][0] = 0.f; zacc[qt][dt][1] = 0.f;
      zacc[qt][dt][2] = 0.f; zacc[qt][dt][3] = 0.f;
    }

  const int kr = tid >> 2;
  const int kc = (tid & 3) << 4;
  const int vd = tid >> 2;
  const int vm = (tid & 3) << 5;

  for (int m0 = 0; m0 < NSEQ / 4; m0 += 128) {
    const ushort_t* ksrc = Kb + h * 262144 + (mbase + m0) * 64;
    const ushort_t* vsrc = Vt + h * 262144 + vd * 4096 + mbase + m0 + vm;
    us8 kst[4], vst[4];
    kst[0] = *(const us8*)(ksrc + kr * 64 + kc);
    kst[1] = *(const us8*)(ksrc + kr * 64 + kc + 8);
    kst[2] = *(const us8*)(ksrc + (64 + kr) * 64 + kc);
    kst[3] = *(const us8*)(ksrc + (64 + kr) * 64 + kc + 8);
#pragma unroll
    for (int j = 0; j < 4; ++j) vst[j] = *(const us8*)(vsrc + j * 8);

    __syncthreads();  // previous chunk's LDS reads complete
    *(us8*)&Ks[kr][kc] = kst[0];
    *(us8*)&Ks[kr][kc + 8] = kst[1];
    *(us8*)&Ks[64 + kr][kc] = kst[2];
    *(us8*)&Ks[64 + kr][kc + 8] = kst[3];
#pragma unroll
    for (int j = 0; j < 4; ++j) *(us8*)&Vts[vd][vm + j * 8] = vst[j];
    __syncthreads();

#pragma unroll
    for (int t = 0; t < 4; ++t) {
      // ---- K fragments for m-pair (mt = 2t, 2t+1); reused by all 4 qt ----
      const half8 kfA0 = *(const half8*)&Ks[(2 * t) * 16 + l16][quad * 8];
      const half8 kfA1 = *(const half8*)&Ks[(2 * t) * 16 + l16][32 + quad * 8];
      const half8 kfB0 = *(const half8*)&Ks[(2 * t + 1) * 16 + l16][quad * 8];
      const half8 kfB1 =
          *(const half8*)&Ks[(2 * t + 1) * 16 + l16][32 + quad * 8];
      // ---- V^T fragments for this m-pair; reused by all 4 qt ----
      half8 vf[4];
#pragma unroll
      for (int dt = 0; dt < 4; ++dt)
        vf[dt] = *(const half8*)&Vts[dt * 16 + l16][t * 32 + quad * 8];

#pragma unroll
      for (int qt = 0; qt < 4; ++qt) {
        floatx4 sA = {0.f, 0.f, 0.f, 0.f};
        sA = __builtin_amdgcn_mfma_f32_16x16x32_f16(kfA0, qf[qt][0], sA, 0, 0, 0);
        sA = __builtin_amdgcn_mfma_f32_16x16x32_f16(kfA1, qf[qt][1], sA, 0, 0, 0);
        floatx4 sB = {0.f, 0.f, 0.f, 0.f};
        sB = __builtin_amdgcn_mfma_f32_16x16x32_f16(kfB0, qf[qt][0], sB, 0, 0, 0);
        sB = __builtin_amdgcn_mfma_f32_16x16x32_f16(kfB1, qf[qt][1], sB, 0, 0, 0);
        const float eA0 = EXP2F(sA[0]), eA1 = EXP2F(sA[1]);
        const float eA2 = EXP2F(sA[2]), eA3 = EXP2F(sA[3]);
        const float eB0 = EXP2F(sB[0]), eB1 = EXP2F(sB[1]);
        const float eB2 = EXP2F(sB[2]), eB3 = EXP2F(sB[3]);
        sl[qt] += ((eA0 + eA1) + (eA2 + eA3)) + ((eB0 + eB1) + (eB2 + eB3));
        union { pkhalf2 h; unsigned u; } a01, a23, b01, b23;
        a01.h = __builtin_amdgcn_cvt_pkrtz(eA0, eA1);
        a23.h = __builtin_amdgcn_cvt_pkrtz(eA2, eA3);
        b01.h = __builtin_amdgcn_cvt_pkrtz(eB0, eB1);
        b23.h = __builtin_amdgcn_cvt_pkrtz(eB2, eB3);
        ushort_t* slot = &Ps[w * 2 + (qt & 1)][l16][0];
        *(unsigned*)(slot + quad * 4) = a01.u;
        *(unsigned*)(slot + quad * 4 + 2) = a23.u;
        *(unsigned*)(slot + 16 + quad * 4) = b01.u;
        *(unsigned*)(slot + 16 + quad * 4 + 2) = b23.u;
        // same-wave LDS RAW: write->read ordered via lgkmcnt (no barrier)
        const half8 pf = *(const half8*)(slot + quad * 8);
#pragma unroll
        for (int dt = 0; dt < 4; ++dt)
          zacc[qt][dt] = __builtin_amdgcn_mfma_f32_16x16x32_f16(
              vf[dt], pf, zacc[qt][dt], 0, 0, 0);
      }
    }
  }

  // ---- partial epilogue: Z^T partials as f16; rowsum quad-reduced ----
#pragma unroll
  for (int qt = 0; qt < 4; ++qt) {
    float s = sl[qt];
    s += __shfl_xor(s, 16, 64);
    s += __shfl_xor(s, 32, 64);
    const int n = n0 + w * 64 + qt * 16 + l16;
    ushort_t* dst = Zp + z * 2097152 + n * EDIM + h * 64;
#pragma unroll
    for (int dt = 0; dt < 4; ++dt) {
      us4 o;
#pragma unroll
      for (int r = 0; r < 4; ++r) o[r] = f2h(zacc[qt][dt][r]);
      *(us4*)(dst + dt * 16 + quad * 4) = o;
    }
    if (quad == 0) Lp[z * 32768 + h * 4096 + n] = s;
  }
}

extern "C" void kernel_launch(void* const* d_in, const int* in_sizes, int n_in,
                              void* d_out, int out_size, void* d_ws,
                              size_t ws_size, hipStream_t stream) {
  const float* inp = (const float*)d_in[0];
  const float* WKw = (const float*)d_in[1];
  const float* WKb = (const float*)d_in[2];
  const float* WQw = (const float*)d_in[3];
  const float* WQb = (const float*)d_in[4];
  const float* WVw = (const float*)d_in[5];
  const float* WVb = (const float*)d_in[6];
  const float* WZw = (const float*)d_in[7];
  const float* WZb = (const float*)d_in[8];

  char* ws = (char*)d_ws;
  const size_t MB = 1 << 20;
  ushort_t* Xf = (ushort_t*)(ws);                        // 4MB; Zf after attn
  ushort_t* WQf = (ushort_t*)(ws + 4 * MB);              // 512KB each
  ushort_t* WKf = (ushort_t*)(ws + 4 * MB + 512 * 1024);
  ushort_t* WVf = (ushort_t*)(ws + 5 * MB);
  ushort_t* WZf = (ushort_t*)(ws + 5 * MB + 512 * 1024);
  ushort_t* Qb = (ushort_t*)(ws + 6 * MB);    // 4MB f16 (E,N) scrambled, *C2
  ushort_t* Kb = (ushort_t*)(ws + 10 * MB);   // 4MB f16 (N,E)
  ushort_t* Vtb = (ushort_t*)(ws + 14 * MB);  // 4MB f16 [h][d][m]
  ushort_t* Zp = (ushort_t*)(ws + 18 * MB);   // 16MB: [4][4096][512] f16
  float* Lp = (float*)(ws + 34 * MB);         // 512KB: [4][8][4096]

  cast_all<<<3072, 256, 0, stream>>>(inp, Xf, WKw, WQw, WVw, WZw, WKf, WQf,
                                     WVf, WZf);

  gemm_qkv<<<dim3(NSEQ / 128, EDIM / 64, 3), 256, 0, stream>>>(
      WQf, WQb, WKf, WKb, WVf, WVb, Xf, Qb, Kb, Vtb);

  attn_mfma<<<dim3(NSEQ / 256, NHEAD, 4), 256, 0, stream>>>(Qb, Kb, Vtb, Zp,
                                                            Lp);

  combine<<<1024, 256, 0, stream>>>(Zp, Lp, Xf);  // Xf reused as Zf

  gemm_out<<<dim3(NSEQ / 64, EDIM / 64), 256, 0, stream>>>(WZf, Xf, WZb,
                                                           (float*)d_out);
}